// Round 13
// baseline (1620.312 us; speedup 1.0000x reference)
//
#include <hip/hip_runtime.h>
#include <math.h>

#define Bb 64
#define Pp 196
#define ENCd 2048
#define Lc 20
#define Tt 19
#define Vv 10000
#define Ee 512
#define Dd 512
#define Aa 512
#define K2 2560     // E + ENC  (x2 = [emb, gate*awe])
#define KG 3072     // E + ENC + D
#define G4 2048     // 4*D
#define NPAD 10112  // Vv padded to 79*128

#define OUT_PRED 0ll
#define OUT_CAPS 12160000ll   // B*T*V
#define OUT_ALPH 12161280ll   // + B*L
#define OUT_SIND 12399616ll   // + B*T*P

typedef unsigned short ushort_t;
typedef __attribute__((ext_vector_type(8))) short short8;
typedef __attribute__((ext_vector_type(4))) float f32x4;

#define MFMA16 __builtin_amdgcn_mfma_f32_16x16x32_bf16

__device__ __forceinline__ float b2f(ushort_t u) {
    union { unsigned int i; float f; } x; x.i = ((unsigned int)u) << 16; return x.f;
}
__device__ __forceinline__ ushort_t f2b(float f) {
    union { float f; unsigned int i; } x; x.f = f;
    unsigned int r = x.i + 0x7fffu + ((x.i >> 16) & 1u);
    return (ushort_t)(r >> 16);
}
__device__ __forceinline__ float fsig(float x) { return 1.0f / (1.0f + __expf(-x)); }
__device__ __forceinline__ float ftanh(float x) {
    x = fminf(fmaxf(x, -15.0f), 15.0f);
    float e = __expf(2.0f * x);
    return (e - 1.0f) / (e + 1.0f);
}

// ---------------- sort (stable descending argsort of caption lengths) --------
__global__ void k_sort(const int* __restrict__ cap_len, const int* __restrict__ caps_in,
                       float* __restrict__ out, int* __restrict__ sind,
                       int* __restrict__ dlen, int* __restrict__ caps_s) {
    __shared__ int cls[Bb];
    int i = threadIdx.x;
    int cl = cap_len[i];
    cls[i] = cl;
    __syncthreads();
    int rank = 0;
    for (int j = 0; j < Bb; ++j) {
        int cj = cls[j];
        rank += (cj > cl) || (cj == cl && j < i);
    }
    sind[rank] = i;
    dlen[rank] = cl - 1;
    out[OUT_SIND + rank] = (float)i;
    for (int l = 0; l < Lc; ++l) {
        int v = caps_in[i * Lc + l];
        caps_s[rank * Lc + l] = v;
        out[OUT_CAPS + rank * Lc + l] = (float)v;
    }
}

// ---------------- merged weight conversions ----------------------------------
__device__ __forceinline__ void cvtseg(const float* __restrict__ src, ushort_t* __restrict__ dst,
                                       int cols, int stride, int off, int bid0, long long quads) {
    long long qid = (long long)bid0 * 256 + threadIdx.x;
    if (qid >= quads) return;
    int c4pr = cols >> 2;
    int r = (int)(qid / c4pr), c4 = (int)(qid % c4pr) << 2;
    float4 v = *(const float4*)&src[(size_t)r * cols + c4];
    ushort4 o; o.x = f2b(v.x); o.y = f2b(v.y); o.z = f2b(v.z); o.w = f2b(v.w);
    *(ushort4*)&dst[(size_t)r * stride + off + c4] = o;
}

__global__ void k_cvtall(const float* Wdec, const float* Wfb, const float* Wih,
                         const float* Whh, const float* Wfc, const float* Wenc_f,
                         const float* Wih0, const float* Wic0,
                         ushort_t* W_ag, ushort_t* W_cat, ushort_t* W_fcb,
                         ushort_t* W_enc, ushort_t* W_hcb) {
    int b = blockIdx.x;
    if      (b < 256)   cvtseg(Wdec,  W_ag,               512,  512,  0,    b,         65536);
    else if (b < 1280)  cvtseg(Wfb,   W_ag + 512 * 512,   512,  512,  0,    b - 256,   262144);
    else if (b < 6400)  cvtseg(Wih,   W_cat,              2560, 3072, 0,    b - 1280,  1310720);
    else if (b < 7424)  cvtseg(Whh,   W_cat,              512,  3072, 2560, b - 6400,  262144);
    else if (b < 12424) cvtseg(Wfc,   W_fcb,              512,  512,  0,    b - 7424,  1280000);
    else if (b < 13448) cvtseg(Wenc_f,W_enc,              2048, 2048, 0,    b - 12424, 262144);
    else if (b < 14472) cvtseg(Wih0,  W_hcb,              2048, 2048, 0,    b - 13448, 262144);
    else                cvtseg(Wic0,  W_hcb + 512 * 2048, 2048, 2048, 0,    b - 14472, 262144);
}

// ---------------- bias prep --------------------------------------------------
__global__ void k_bias(const float* b_dec, const float* b_fb, const float* b_ihp,
                       const float* b_hhp, const float* b_h, const float* b_c,
                       float* b_ag, float* bsum, float* b_hc) {
    int id = blockIdx.x * 256 + threadIdx.x;
    if (id < 512) b_ag[id] = b_dec[id];
    else if (id < 2560) b_ag[id] = b_fb[id - 512];
    if (id < 2048) bsum[id] = b_ihp[id] + b_hhp[id];
    if (id < 512) b_hc[id] = b_h[id];
    else if (id < 1024) b_hc[id] = b_c[id - 512];
}

// ---------------- gather+convert encoder_out (sorted) -> bf16 ----------------
__global__ void __launch_bounds__(256) k_enccvt(const float* __restrict__ enc,
                                                const int* __restrict__ sind,
                                                ushort_t* __restrict__ enc_bf) {
    const long long total8 = (long long)Bb * Pp * ENCd / 8;   // 3,211,264
    for (long long u = (long long)blockIdx.x * 256 + threadIdx.x; u < total8;
         u += (long long)gridDim.x * 256) {
        long long flat = u * 8;
        int r = (int)(flat >> 11);
        int c8 = (int)(flat & 2047);
        int b = r / Pp;
        size_t srow = (size_t)sind[b] * Pp + (r - b * Pp);
        const float* s = enc + srow * ENCd + c8;
        float4 v0 = *(const float4*)s;
        float4 v1 = *(const float4*)(s + 4);
        short8 o;
        o[0] = (short)f2b(v0.x); o[1] = (short)f2b(v0.y); o[2] = (short)f2b(v0.z); o[3] = (short)f2b(v0.w);
        o[4] = (short)f2b(v1.x); o[5] = (short)f2b(v1.y); o[6] = (short)f2b(v1.z); o[7] = (short)f2b(v1.w);
        *(short8*)&enc_bf[(size_t)r * ENCd + c8] = o;
    }
}

// ---------------- mean over pixels (from bf16) -------------------------------
__global__ void __launch_bounds__(1024) k_meanenc(const ushort_t* __restrict__ enc_bf,
                                                  ushort_t* __restrict__ mean_bf) {
    int b = blockIdx.x;
    int lane = threadIdx.x & 63, w = threadIdx.x >> 6;
    int cg = w & 3, pg = w >> 2;
    int lc = cg * 512 + lane * 8;
    __shared__ float red[4][2048];
    float acc[8] = {};
    for (int p = pg; p < Pp; p += 4) {
        short8 v = *(const short8*)&enc_bf[((size_t)b * Pp + p) * ENCd + lc];
        #pragma unroll
        for (int j = 0; j < 8; ++j) acc[j] += b2f((ushort_t)v[j]);
    }
    #pragma unroll
    for (int j = 0; j < 8; ++j) red[pg][lc + j] = acc[j];
    __syncthreads();
    int tid = threadIdx.x;
    float2 s = {0.f, 0.f};
    #pragma unroll
    for (int g = 0; g < 4; ++g) {
        float2 v = *(const float2*)&red[g][tid * 2];
        s.x += v.x; s.y += v.y;
    }
    ushort2 o; o.x = f2b(s.x * (1.0f / Pp)); o.y = f2b(s.y * (1.0f / Pp));
    *(ushort2*)&mean_bf[(size_t)b * ENCd + tid * 2] = o;
}

// ---------------- att1: LDS-staged 128x128x64 tile GEMM, XCD-swizzled --------
__global__ void __launch_bounds__(256) k_att1(const ushort_t* __restrict__ enc_bf,
                                              const ushort_t* __restrict__ Wenc,
                                              const float* __restrict__ benc,
                                              ushort_t* __restrict__ att1) {
    __shared__ ushort_t As[128 * 64];
    __shared__ ushort_t Bs[128 * 64];
    int tid = threadIdx.x;
    int lane = tid & 63, w = tid >> 6;
    int wr = w >> 1, wc = w & 1;
    int d = blockIdx.x;
    int lid = (d & 7) * 49 + (d >> 3);
    int by = lid >> 2, bx = lid & 3;
    int m0 = by * 128, n0 = bx * 128;
    int r16 = lane & 15;
    f32x4 acc[4][4];
    #pragma unroll
    for (int mf = 0; mf < 4; ++mf)
        #pragma unroll
        for (int nf = 0; nf < 4; ++nf) acc[mf][nf] = (f32x4){0.f, 0.f, 0.f, 0.f};

    int lrow = lane >> 3;
    int lslot = lane & 7;
    for (int k0 = 0; k0 < ENCd; k0 += 64) {
        __syncthreads();
        #pragma unroll
        for (int c = 0; c < 4; ++c) {
            int row = c * 32 + w * 8 + lrow;
            int kg = lslot ^ (row & 7);
            const ushort_t* asrc = enc_bf + (size_t)(m0 + row) * ENCd + k0 + kg * 8;
            const ushort_t* bsrc = Wenc   + (size_t)(n0 + row) * ENCd + k0 + kg * 8;
            __builtin_amdgcn_global_load_lds(
                (const __attribute__((address_space(1))) void*)asrc,
                (__attribute__((address_space(3))) void*)&As[(c * 32 + w * 8) * 64], 16, 0, 0);
            __builtin_amdgcn_global_load_lds(
                (const __attribute__((address_space(1))) void*)bsrc,
                (__attribute__((address_space(3))) void*)&Bs[(c * 32 + w * 8) * 64], 16, 0, 0);
        }
        __syncthreads();
        #pragma unroll
        for (int ks = 0; ks < 2; ++ks) {
            int sl = ks * 4 + (lane >> 4);
            short8 a[4], b[4];
            #pragma unroll
            for (int mf = 0; mf < 4; ++mf) {
                int row = wr * 64 + mf * 16 + r16;
                a[mf] = *(const short8*)&As[row * 64 + ((sl ^ (row & 7)) << 3)];
            }
            #pragma unroll
            for (int nf = 0; nf < 4; ++nf) {
                int row = wc * 64 + nf * 16 + r16;
                b[nf] = *(const short8*)&Bs[row * 64 + ((sl ^ (row & 7)) << 3)];
            }
            #pragma unroll
            for (int mf = 0; mf < 4; ++mf)
                #pragma unroll
                for (int nf = 0; nf < 4; ++nf)
                    acc[mf][nf] = MFMA16(a[mf], b[nf], acc[mf][nf], 0, 0, 0);
        }
    }
    int rj0 = (lane >> 4) << 2;
    #pragma unroll
    for (int mf = 0; mf < 4; ++mf)
        #pragma unroll
        for (int nf = 0; nf < 4; ++nf) {
            int col = n0 + wc * 64 + nf * 16 + r16;
            float bv = benc[col];
            #pragma unroll
            for (int j = 0; j < 4; ++j) {
                int row = m0 + wr * 64 + mf * 16 + rj0 + j;
                att1[(size_t)row * Aa + col] = f2b(acc[mf][nf][j] + bv);
            }
        }
}

// ---------------- h0/c0 small GEMM (split-K over 4 waves) --------------------
__global__ void __launch_bounds__(256) k_h0c0(
        const ushort_t* __restrict__ A, const ushort_t* __restrict__ W,
        const float* __restrict__ bias, ushort_t* __restrict__ hout,
        float* __restrict__ cst) {
    int lane = threadIdx.x & 63, w = threadIdx.x >> 6;
    int r16 = lane & 15, kq = (lane >> 4) << 3;
    int ncol[4];
    #pragma unroll
    for (int tt = 0; tt < 4; ++tt) ncol[tt] = blockIdx.x * 64 + tt * 16 + r16;
    f32x4 acc[4][4];
    #pragma unroll
    for (int mt = 0; mt < 4; ++mt)
        #pragma unroll
        for (int tt = 0; tt < 4; ++tt) acc[mt][tt] = (f32x4){0.f, 0.f, 0.f, 0.f};
    for (int k0 = w * 512; k0 < w * 512 + 512; k0 += 32) {
        short8 a[4];
        #pragma unroll
        for (int mt = 0; mt < 4; ++mt)
            a[mt] = *(const short8*)(A + (size_t)(mt * 16 + r16) * ENCd + k0 + kq);
        #pragma unroll
        for (int tt = 0; tt < 4; ++tt) {
            short8 bw = *(const short8*)&W[(size_t)ncol[tt] * ENCd + k0 + kq];
            #pragma unroll
            for (int mt = 0; mt < 4; ++mt)
                acc[mt][tt] = MFMA16(a[mt], bw, acc[mt][tt], 0, 0, 0);
        }
    }
    __shared__ float red[2][64][68];
    if (w >= 2) {
        float* row = &red[w - 2][lane][0];
        #pragma unroll
        for (int mt = 0; mt < 4; ++mt)
            #pragma unroll
            for (int tt = 0; tt < 4; ++tt) *(f32x4*)&row[(mt * 4 + tt) * 4] = acc[mt][tt];
    }
    __syncthreads();
    if (w < 2) {
        float* row = &red[w][lane][0];
        #pragma unroll
        for (int mt = 0; mt < 4; ++mt)
            #pragma unroll
            for (int tt = 0; tt < 4; ++tt) acc[mt][tt] += *(f32x4*)&row[(mt * 4 + tt) * 4];
    }
    __syncthreads();
    if (w == 1) {
        float* row = &red[0][lane][0];
        #pragma unroll
        for (int mt = 0; mt < 4; ++mt)
            #pragma unroll
            for (int tt = 0; tt < 4; ++tt) *(f32x4*)&row[(mt * 4 + tt) * 4] = acc[mt][tt];
    }
    __syncthreads();
    if (w != 0) return;
    {
        float* row = &red[0][lane][0];
        #pragma unroll
        for (int mt = 0; mt < 4; ++mt)
            #pragma unroll
            for (int tt = 0; tt < 4; ++tt) acc[mt][tt] += *(f32x4*)&row[(mt * 4 + tt) * 4];
    }
    int rj0 = (lane >> 4) << 2;
    #pragma unroll
    for (int mt = 0; mt < 4; ++mt)
        #pragma unroll
        for (int tt = 0; tt < 4; ++tt) {
            int col = ncol[tt];
            float bv = bias[col];
            #pragma unroll
            for (int j = 0; j < 4; ++j) {
                int row = mt * 16 + rj0 + j;
                float v = acc[mt][tt][j] + bv;
                if (col < 512) hout[row * Dd + col] = f2b(v);
                else           cst[row * Dd + (col - 512)] = v;
            }
        }
}

// ---------------- fused ag-matvec(MFMA) + e-score + softmax + awe ------------
// grid 256: block (b = bid>>2, ch = bid&3). Each block computes att2[512] and
// its own gate slice via broadcast-A MFMA (A rows = h[b] replicated).
__global__ void __launch_bounds__(1024) k_esmawe(
        const ushort_t* __restrict__ att1, const ushort_t* __restrict__ hcur,
        const ushort_t* __restrict__ W_ag, const float* __restrict__ b_ag,
        const float* __restrict__ wfull, const float* __restrict__ bfull,
        const ushort_t* __restrict__ enc_bf,
        const float* __restrict__ emb, const int* __restrict__ caps_s,
        ushort_t* __restrict__ x2, float* __restrict__ out,
        const int* __restrict__ dlen, int t) {
    int b = blockIdx.x >> 2, ch = blockIdx.x & 3;
    int tid = threadIdx.x;
    int lane = tid & 63, wv = tid >> 6;
    __shared__ float att2f[512], gate_sh[512], wfl[512];
    __shared__ float e_sh[200], al_sh[200], sm[4];
    __shared__ float redA[16][512];
    // --- ag matvec: 64 col-tiles (0-31 att2, 32-63 gate[ch]) , 4 tiles/wave ---
    {
        const ushort_t* hb = hcur + (size_t)b * Dd;
        int r16 = lane & 15, kq = (lane >> 4) << 3;
        f32x4 acc[4];
        #pragma unroll
        for (int i = 0; i < 4; ++i) acc[i] = (f32x4){0.f, 0.f, 0.f, 0.f};
        int t0 = wv * 4;
        const ushort_t* wbase[4];
        #pragma unroll
        for (int i = 0; i < 4; ++i) {
            int tile = t0 + i;
            int wrow = (tile < 32) ? tile * 16 : 512 + ch * 512 + (tile - 32) * 16;
            wbase[i] = W_ag + (size_t)(wrow + r16) * Dd + kq;
        }
        for (int k0 = 0; k0 < Dd; k0 += 32) {
            short8 a = *(const short8*)(hb + k0 + kq);
            #pragma unroll
            for (int i = 0; i < 4; ++i) {
                short8 bw = *(const short8*)(wbase[i] + k0);
                acc[i] = MFMA16(a, bw, acc[i], 0, 0, 0);
            }
        }
        if (lane < 16) {
            #pragma unroll
            for (int i = 0; i < 4; ++i) {
                int tile = t0 + i;
                if (tile < 32) {
                    int col = tile * 16 + lane;
                    att2f[col] = acc[i][0] + b_ag[col];
                } else {
                    int col = (tile - 32) * 16 + lane;
                    gate_sh[col] = fsig(acc[i][0] + b_ag[512 + ch * 512 + col]);
                }
            }
        }
    }
    if (tid >= 512) wfl[tid - 512] = wfull[tid - 512];
    __syncthreads();
    // --- e-scores, 2-way p unroll ---
    float a2[8], wf8[8];
    #pragma unroll
    for (int j = 0; j < 8; ++j) { a2[j] = att2f[lane * 8 + j]; wf8[j] = wfl[lane * 8 + j]; }
    float bf0 = bfull[0];
    for (int p0 = wv; p0 < Pp; p0 += 32) {
        int p1 = p0 + 16;
        bool has1 = p1 < Pp;
        short8 v0 = *(const short8*)&att1[((size_t)b * Pp + p0) * Aa + lane * 8];
        short8 v1 = has1 ? *(const short8*)&att1[((size_t)b * Pp + p1) * Aa + lane * 8] : v0;
        float s0 = 0.f, s1 = 0.f;
        #pragma unroll
        for (int j = 0; j < 8; ++j) {
            s0 += ftanh(b2f((ushort_t)v0[j]) + a2[j]) * wf8[j];
            s1 += ftanh(b2f((ushort_t)v1[j]) + a2[j]) * wf8[j];
        }
        #pragma unroll
        for (int o = 32; o; o >>= 1) {
            s0 += __shfl_xor(s0, o);
            s1 += __shfl_xor(s1, o);
        }
        if (lane == 0) {
            e_sh[p0] = s0 + bf0;
            if (has1) e_sh[p1] = s1 + bf0;
        }
    }
    __syncthreads();
    // --- wave-0 softmax reduce; (ch==0) waves 8-11 emb gather concurrently ---
    if (wv == 0) {
        float v0 = e_sh[lane];
        float v1 = e_sh[lane + 64];
        float v2 = e_sh[lane + 128];
        float v3 = (lane + 192 < Pp) ? e_sh[lane + 192] : -1e30f;
        float m = fmaxf(fmaxf(v0, v1), fmaxf(v2, v3));
        #pragma unroll
        for (int o = 32; o; o >>= 1) m = fmaxf(m, __shfl_xor(m, o));
        float ss = __expf(v0 - m) + __expf(v1 - m) + __expf(v2 - m) + __expf(v3 - m);
        #pragma unroll
        for (int o = 32; o; o >>= 1) ss += __shfl_xor(ss, o);
        if (lane == 0) { sm[0] = m; sm[1] = 1.0f / ss; }
    } else if (ch == 0 && tid >= 512 && tid < 768) {
        int q = tid - 512;
        float2 e2v = *(const float2*)&emb[(size_t)caps_s[b * Lc + t] * Ee + q * 2];
        ushort2 o2; o2.x = f2b(e2v.x); o2.y = f2b(e2v.y);
        *(ushort2*)&x2[(size_t)b * K2 + q * 2] = o2;
    }
    __syncthreads();
    float mx = sm[0], inv = sm[1];
    if (tid < Pp) {
        float al = __expf(e_sh[tid] - mx) * inv;
        al_sh[tid] = al;
        if (ch == 0)
            out[OUT_ALPH + ((long long)b * Tt + t) * Pp + tid] = (t < dlen[b]) ? al : 0.0f;
    }
    __syncthreads();
    // --- awe over this block's 512 cols ---
    {
        int cg = tid & 63, pg = tid >> 6;
        int c0 = cg * 8;
        float acc[8] = {};
        const ushort_t* ep = enc_bf + (size_t)b * Pp * ENCd + ch * 512 + c0;
        for (int p = pg; p < Pp; p += 16) {
            float a = al_sh[p];
            short8 vv = *(const short8*)(ep + (size_t)p * ENCd);
            #pragma unroll
            for (int j = 0; j < 8; ++j) acc[j] += a * b2f((ushort_t)vv[j]);
        }
        *(f32x4*)&redA[pg][c0]     = *(f32x4*)&acc[0];
        *(f32x4*)&redA[pg][c0 + 4] = *(f32x4*)&acc[4];
    }
    __syncthreads();
    if (tid < 512) {
        float s = 0.f;
        #pragma unroll
        for (int g = 0; g < 16; ++g) s += redA[g][tid];
        int col = ch * 512 + tid;
        x2[(size_t)b * K2 + Ee + col] = f2b(gate_sh[tid] * s);
    }
}

// ---------------- gates GEMM + LSTM, 512 threads (8-wave split-K) ------------
__global__ void __launch_bounds__(512) k_gates(
        const ushort_t* __restrict__ x2, const ushort_t* __restrict__ hin,
        const ushort_t* __restrict__ Wcat, const float* __restrict__ bsum,
        ushort_t* __restrict__ hout, float* __restrict__ cst,
        const int* __restrict__ dlen, int t) {
    int lane = threadIdx.x & 63, w = threadIdx.x >> 6;   // 8 waves
    int r16 = lane & 15, kq = (lane >> 4) << 3;
    int m0 = blockIdx.y * 16;
    int d0 = blockIdx.x * 16;
    int row = m0 + r16;
    f32x4 acc[4];
    #pragma unroll
    for (int tt = 0; tt < 4; ++tt) acc[tt] = (f32x4){0.f, 0.f, 0.f, 0.f};
    for (int k0 = w * 384; k0 < w * 384 + 384; k0 += 32) {
        const ushort_t* s = (k0 < K2) ? (x2 + (size_t)row * K2 + k0 + kq)
                                      : (hin + (size_t)row * Dd + (k0 - K2) + kq);
        short8 a = *(const short8*)s;
        #pragma unroll
        for (int tt = 0; tt < 4; ++tt) {
            short8 bw = *(const short8*)&Wcat[(size_t)(d0 + tt * 512 + r16) * KG + k0 + kq];
            acc[tt] = MFMA16(a, bw, acc[tt], 0, 0, 0);
        }
    }
    __shared__ float red[4][64][20];
    for (int s2 = 4; s2; s2 >>= 1) {
        if (w >= s2 && w < 2 * s2) {
            float* rr = &red[w - s2][lane][0];
            #pragma unroll
            for (int tt = 0; tt < 4; ++tt) *(f32x4*)&rr[tt * 4] = acc[tt];
        }
        __syncthreads();
        if (w < s2) {
            float* rr = &red[w][lane][0];
            #pragma unroll
            for (int tt = 0; tt < 4; ++tt) acc[tt] += *(f32x4*)&rr[tt * 4];
        }
        __syncthreads();
    }
    if (w != 0) return;
    int rj0 = (lane >> 4) << 2;
    int d = d0 + r16;
    #pragma unroll
    for (int j = 0; j < 4; ++j) {
        int rw = m0 + rj0 + j;
        ushort_t hb;
        if (t < dlen[rw]) {
            float gi = acc[0][j] + bsum[d];
            float gf = acc[1][j] + bsum[512 + d];
            float gg = acc[2][j] + bsum[1024 + d];
            float go = acc[3][j] + bsum[1536 + d];
            float cv = cst[rw * Dd + d];
            float cn = fsig(gf) * cv + fsig(gi) * ftanh(gg);
            cst[rw * Dd + d] = cn;
            hb = f2b(fsig(go) * ftanh(cn));
        } else {
            hb = hin[rw * Dd + d];
        }
        hout[rw * Dd + d] = hb;
    }
}

// ---------------- batched preds: LDS-staged 128x128x64 tile GEMM -------------
__global__ void __launch_bounds__(256) k_preds(
        const ushort_t* __restrict__ hA, const ushort_t* __restrict__ Wfc,
        const float* __restrict__ bfc, const int* __restrict__ dlen,
        float* __restrict__ out) {
    __shared__ ushort_t As[128 * 64];
    __shared__ ushort_t Bs[128 * 64];
    __shared__ float wb[4][16][66];
    int tid = threadIdx.x;
    int lane = tid & 63, w = tid >> 6;
    int wr = w >> 1, wc = w & 1;
    int d = blockIdx.x;
    int x = d & 7, k = d >> 3;
    int lid = (x < 6 ? x * 99 : 594 + (x - 6) * 98) + k;
    int bx = lid / 10, by = lid % 10;
    int m0 = by * 128, n0 = bx * 128;
    int r16 = lane & 15;
    f32x4 acc[4][4];
    #pragma unroll
    for (int mf = 0; mf < 4; ++mf)
        #pragma unroll
        for (int nf = 0; nf < 4; ++nf) acc[mf][nf] = (f32x4){0.f, 0.f, 0.f, 0.f};

    int lrow = lane >> 3;
    int lslot = lane & 7;
    for (int k0 = 0; k0 < Dd; k0 += 64) {
        __syncthreads();
        #pragma unroll
        for (int c = 0; c < 4; ++c) {
            int row = c * 32 + w * 8 + lrow;
            int kg = lslot ^ (row & 7);
            const ushort_t* asrc = hA  + (size_t)(m0 + row) * Dd + k0 + kg * 8;
            const ushort_t* bsrc = Wfc + (size_t)(n0 + row) * Dd + k0 + kg * 8;
            __builtin_amdgcn_global_load_lds(
                (const __attribute__((address_space(1))) void*)asrc,
                (__attribute__((address_space(3))) void*)&As[(c * 32 + w * 8) * 64], 16, 0, 0);
            __builtin_amdgcn_global_load_lds(
                (const __attribute__((address_space(1))) void*)bsrc,
                (__attribute__((address_space(3))) void*)&Bs[(c * 32 + w * 8) * 64], 16, 0, 0);
        }
        __syncthreads();
        #pragma unroll
        for (int ks = 0; ks < 2; ++ks) {
            int sl = ks * 4 + (lane >> 4);
            short8 a[4], b[4];
            #pragma unroll
            for (int mf = 0; mf < 4; ++mf) {
                int row = wr * 64 + mf * 16 + r16;
                a[mf] = *(const short8*)&As[row * 64 + ((sl ^ (row & 7)) << 3)];
            }
            #pragma unroll
            for (int nf = 0; nf < 4; ++nf) {
                int row = wc * 64 + nf * 16 + r16;
                b[nf] = *(const short8*)&Bs[row * 64 + ((sl ^ (row & 7)) << 3)];
            }
            #pragma unroll
            for (int mf = 0; mf < 4; ++mf)
                #pragma unroll
                for (int nf = 0; nf < 4; ++nf)
                    acc[mf][nf] = MFMA16(a[mf], b[nf], acc[mf][nf], 0, 0, 0);
        }
    }
    int rj0 = (lane >> 4) << 2;
    #pragma unroll
    for (int mf = 0; mf < 4; ++mf) {
        #pragma unroll
        for (int nf = 0; nf < 4; ++nf) {
            float bv = bfc[n0 + wc * 64 + nf * 16 + r16];
            #pragma unroll
            for (int j = 0; j < 4; ++j)
                wb[w][rj0 + j][nf * 16 + r16] = acc[mf][nf][j] + bv;
        }
        asm volatile("s_waitcnt lgkmcnt(0)" ::: "memory");
        #pragma unroll
        for (int c = 0; c < 4; ++c) {
            int idx = c * 64 + lane;
            int row16 = idx >> 4, c4 = idx & 15;
            int grow = m0 + wr * 64 + mf * 16 + row16;
            int gcol = n0 + wc * 64 + c4 * 4;
            if (grow < 1216 && gcol < Vv) {
                int ts = grow >> 6, b = grow & 63;
                f32x4 v = *(f32x4*)&wb[w][row16][c4 * 4];
                if (ts >= dlen[b]) v = (f32x4){0.f, 0.f, 0.f, 0.f};
                __builtin_nontemporal_store(v,
                    (f32x4*)&out[OUT_PRED + ((long long)b * Tt + ts) * Vv + gcol]);
            }
        }
        asm volatile("s_waitcnt vmcnt(0)" ::: "memory");
    }
}

extern "C" void kernel_launch(void* const* d_in, const int* in_sizes, int n_in,
                              void* d_out, int out_size, void* d_ws, size_t ws_size,
                              hipStream_t stream) {
    const float* encoder_out      = (const float*)d_in[0];
    const int*   encoded_captions = (const int*)d_in[1];
    const int*   caption_lengths  = (const int*)d_in[2];
    const float* emb       = (const float*)d_in[3];
    const float* W_ih      = (const float*)d_in[4];
    const float* b_ih      = (const float*)d_in[5];
    const float* W_hh      = (const float*)d_in[6];
    const float* b_hh      = (const float*)d_in[7];
    const float* W_init_h  = (const float*)d_in[8];
    const float* b_init_h  = (const float*)d_in[9];
    const float* W_init_c  = (const float*)d_in[10];
    const float* b_init_c  = (const float*)d_in[11];
    const float* W_fbeta   = (const float*)d_in[12];
    const float* b_fbeta   = (const float*)d_in[13];
    const float* W_fc      = (const float*)d_in[14];
    const float* b_fc      = (const float*)d_in[15];
    const float* W_enc_att = (const float*)d_in[16];
    const float* b_enc_att = (const float*)d_in[17];
    const float* W_dec_att = (const float*)d_in[18];
    const float* b_dec_att = (const float*)d_in[19];
    const float* W_full_att = (const float*)d_in[20];
    const float* b_full_att = (const float*)d_in[21];
    float* out = (float*)d_out;

    char* p = (char*)d_ws;
    auto alloc = [&](size_t bytes) { char* r = p; p += (bytes + 255) & ~255ull; return r; };
    int* sind   = (int*)alloc(64 * 4);
    int* dlen   = (int*)alloc(64 * 4);
    int* caps_s = (int*)alloc(Bb * Lc * 4);
    float* c_st  = (float*)alloc(Bb * Dd * 4);
    float* b_ag  = (float*)alloc(K2 * 4);
    float* bsum  = (float*)alloc(G4 * 4);
    float* b_hc  = (float*)alloc(1024 * 4);
    ushort_t* mean_bf = (ushort_t*)alloc((size_t)Bb * ENCd * 2);
    ushort_t* hball   = (ushort_t*)alloc((size_t)(Tt + 2) * Bb * Dd * 2);
    ushort_t* x2      = (ushort_t*)alloc((size_t)Bb * K2 * 2);
    ushort_t* att1    = (ushort_t*)alloc((size_t)Bb * Pp * Aa * 2);
    ushort_t* W_enc   = (ushort_t*)alloc((size_t)Aa * ENCd * 2);
    ushort_t* W_ag    = (ushort_t*)alloc((size_t)K2 * Dd * 2);
    ushort_t* W_cat   = (ushort_t*)alloc((size_t)G4 * KG * 2);
    ushort_t* W_fcb   = (ushort_t*)alloc((size_t)NPAD * Dd * 2);
    ushort_t* W_hcb   = (ushort_t*)alloc((size_t)1024 * ENCd * 2);
    ushort_t* enc_bf  = (ushort_t*)alloc((size_t)Bb * Pp * ENCd * 2);

    k_sort<<<1, 64, 0, stream>>>(caption_lengths, encoded_captions, out, sind, dlen, caps_s);
    k_cvtall<<<15496, 256, 0, stream>>>(W_dec_att, W_fbeta, W_ih, W_hh, W_fc, W_enc_att,
                                        W_init_h, W_init_c, W_ag, W_cat, W_fcb, W_enc, W_hcb);
    k_bias<<<10, 256, 0, stream>>>(b_dec_att, b_fbeta, b_ih, b_hh, b_init_h, b_init_c,
                                   b_ag, bsum, b_hc);
    k_enccvt<<<2048, 256, 0, stream>>>(encoder_out, sind, enc_bf);
    k_meanenc<<<64, 1024, 0, stream>>>(enc_bf, mean_bf);
    k_h0c0<<<16, 256, 0, stream>>>(mean_bf, W_hcb, b_hc, hball, c_st);
    k_att1<<<392, 256, 0, stream>>>(enc_bf, W_enc, b_enc_att, att1);

    for (int t = 0; t < Tt; ++t) {
        const ushort_t* hcur = hball + (size_t)t * Bb * Dd;
        ushort_t* hnext = hball + (size_t)(t + 1) * Bb * Dd;
        k_esmawe<<<256, 1024, 0, stream>>>(att1, hcur, W_ag, b_ag, W_full_att, b_full_att,
            enc_bf, emb, caps_s, x2, out, dlen, t);
        k_gates<<<dim3(32, 4), 512, 0, stream>>>(x2, hcur, W_cat, bsum, hnext, c_st, dlen, t);
    }
    k_preds<<<790, 256, 0, stream>>>(hball + (size_t)Bb * Dd, W_fcb, b_fc, dlen, out);
}

// Round 14
// 1186.317 us; speedup vs baseline: 1.3658x; 1.3658x over previous
//
#include <hip/hip_runtime.h>
#include <math.h>

#define Bb 64
#define Pp 196
#define ENCd 2048
#define Lc 20
#define Tt 19
#define Vv 10000
#define Ee 512
#define Dd 512
#define Aa 512
#define K2 2560     // E + ENC  (x2 = [emb, gate*awe])
#define KG 3072     // E + ENC + D
#define G4 2048     // 4*D
#define NPAD 10112  // Vv padded to 79*128

#define OUT_PRED 0ll
#define OUT_CAPS 12160000ll   // B*T*V
#define OUT_ALPH 12161280ll   // + B*L
#define OUT_SIND 12399616ll   // + B*T*P

typedef unsigned short ushort_t;
typedef __attribute__((ext_vector_type(8))) short short8;
typedef __attribute__((ext_vector_type(4))) float f32x4;

#define MFMA16 __builtin_amdgcn_mfma_f32_16x16x32_bf16

__device__ __forceinline__ float b2f(ushort_t u) {
    union { unsigned int i; float f; } x; x.i = ((unsigned int)u) << 16; return x.f;
}
__device__ __forceinline__ ushort_t f2b(float f) {
    union { float f; unsigned int i; } x; x.f = f;
    unsigned int r = x.i + 0x7fffu + ((x.i >> 16) & 1u);
    return (ushort_t)(r >> 16);
}
__device__ __forceinline__ float fsig(float x) { return 1.0f / (1.0f + __expf(-x)); }
__device__ __forceinline__ float ftanh(float x) {
    x = fminf(fmaxf(x, -15.0f), 15.0f);
    float e = __expf(2.0f * x);
    return (e - 1.0f) / (e + 1.0f);
}

// ---------------- sort (stable descending argsort of caption lengths) --------
__global__ void k_sort(const int* __restrict__ cap_len, const int* __restrict__ caps_in,
                       float* __restrict__ out, int* __restrict__ sind,
                       int* __restrict__ dlen, int* __restrict__ caps_s) {
    __shared__ int cls[Bb];
    int i = threadIdx.x;
    int cl = cap_len[i];
    cls[i] = cl;
    __syncthreads();
    int rank = 0;
    for (int j = 0; j < Bb; ++j) {
        int cj = cls[j];
        rank += (cj > cl) || (cj == cl && j < i);
    }
    sind[rank] = i;
    dlen[rank] = cl - 1;
    out[OUT_SIND + rank] = (float)i;
    for (int l = 0; l < Lc; ++l) {
        int v = caps_in[i * Lc + l];
        caps_s[rank * Lc + l] = v;
        out[OUT_CAPS + rank * Lc + l] = (float)v;
    }
}

// ---------------- merged weight conversions ----------------------------------
__device__ __forceinline__ void cvtseg(const float* __restrict__ src, ushort_t* __restrict__ dst,
                                       int cols, int stride, int off, int bid0, long long quads) {
    long long qid = (long long)bid0 * 256 + threadIdx.x;
    if (qid >= quads) return;
    int c4pr = cols >> 2;
    int r = (int)(qid / c4pr), c4 = (int)(qid % c4pr) << 2;
    float4 v = *(const float4*)&src[(size_t)r * cols + c4];
    ushort4 o; o.x = f2b(v.x); o.y = f2b(v.y); o.z = f2b(v.z); o.w = f2b(v.w);
    *(ushort4*)&dst[(size_t)r * stride + off + c4] = o;
}

__global__ void k_cvtall(const float* Wdec, const float* Wfb, const float* Wih,
                         const float* Whh, const float* Wfc, const float* Wenc_f,
                         const float* Wih0, const float* Wic0,
                         ushort_t* W_ag, ushort_t* W_cat, ushort_t* W_fcb,
                         ushort_t* W_enc, ushort_t* W_hcb) {
    int b = blockIdx.x;
    if      (b < 256)   cvtseg(Wdec,  W_ag,               512,  512,  0,    b,         65536);
    else if (b < 1280)  cvtseg(Wfb,   W_ag + 512 * 512,   512,  512,  0,    b - 256,   262144);
    else if (b < 6400)  cvtseg(Wih,   W_cat,              2560, 3072, 0,    b - 1280,  1310720);
    else if (b < 7424)  cvtseg(Whh,   W_cat,              512,  3072, 2560, b - 6400,  262144);
    else if (b < 12424) cvtseg(Wfc,   W_fcb,              512,  512,  0,    b - 7424,  1280000);
    else if (b < 13448) cvtseg(Wenc_f,W_enc,              2048, 2048, 0,    b - 12424, 262144);
    else if (b < 14472) cvtseg(Wih0,  W_hcb,              2048, 2048, 0,    b - 13448, 262144);
    else                cvtseg(Wic0,  W_hcb + 512 * 2048, 2048, 2048, 0,    b - 14472, 262144);
}

// ---------------- bias prep --------------------------------------------------
__global__ void k_bias(const float* b_dec, const float* b_fb, const float* b_ihp,
                       const float* b_hhp, const float* b_h, const float* b_c,
                       float* b_ag, float* bsum, float* b_hc) {
    int id = blockIdx.x * 256 + threadIdx.x;
    if (id < 512) b_ag[id] = b_dec[id];
    else if (id < 2560) b_ag[id] = b_fb[id - 512];
    if (id < 2048) bsum[id] = b_ihp[id] + b_hhp[id];
    if (id < 512) b_hc[id] = b_h[id];
    else if (id < 1024) b_hc[id] = b_c[id - 512];
}

// ---------------- gather+convert encoder_out (sorted) -> bf16 ----------------
__global__ void __launch_bounds__(256) k_enccvt(const float* __restrict__ enc,
                                                const int* __restrict__ sind,
                                                ushort_t* __restrict__ enc_bf) {
    const long long total8 = (long long)Bb * Pp * ENCd / 8;
    for (long long u = (long long)blockIdx.x * 256 + threadIdx.x; u < total8;
         u += (long long)gridDim.x * 256) {
        long long flat = u * 8;
        int r = (int)(flat >> 11);
        int c8 = (int)(flat & 2047);
        int b = r / Pp;
        size_t srow = (size_t)sind[b] * Pp + (r - b * Pp);
        const float* s = enc + srow * ENCd + c8;
        float4 v0 = *(const float4*)s;
        float4 v1 = *(const float4*)(s + 4);
        short8 o;
        o[0] = (short)f2b(v0.x); o[1] = (short)f2b(v0.y); o[2] = (short)f2b(v0.z); o[3] = (short)f2b(v0.w);
        o[4] = (short)f2b(v1.x); o[5] = (short)f2b(v1.y); o[6] = (short)f2b(v1.z); o[7] = (short)f2b(v1.w);
        *(short8*)&enc_bf[(size_t)r * ENCd + c8] = o;
    }
}

// ---------------- mean over pixels (from bf16) -------------------------------
__global__ void __launch_bounds__(1024) k_meanenc(const ushort_t* __restrict__ enc_bf,
                                                  ushort_t* __restrict__ mean_bf) {
    int b = blockIdx.x;
    int lane = threadIdx.x & 63, w = threadIdx.x >> 6;
    int cg = w & 3, pg = w >> 2;
    int lc = cg * 512 + lane * 8;
    __shared__ float red[4][2048];
    float acc[8] = {};
    for (int p = pg; p < Pp; p += 4) {
        short8 v = *(const short8*)&enc_bf[((size_t)b * Pp + p) * ENCd + lc];
        #pragma unroll
        for (int j = 0; j < 8; ++j) acc[j] += b2f((ushort_t)v[j]);
    }
    #pragma unroll
    for (int j = 0; j < 8; ++j) red[pg][lc + j] = acc[j];
    __syncthreads();
    int tid = threadIdx.x;
    float2 s = {0.f, 0.f};
    #pragma unroll
    for (int g = 0; g < 4; ++g) {
        float2 v = *(const float2*)&red[g][tid * 2];
        s.x += v.x; s.y += v.y;
    }
    ushort2 o; o.x = f2b(s.x * (1.0f / Pp)); o.y = f2b(s.y * (1.0f / Pp));
    *(ushort2*)&mean_bf[(size_t)b * ENCd + tid * 2] = o;
}

// ---------------- att1: LDS-staged 128x128x64 tile GEMM, XCD-swizzled --------
__global__ void __launch_bounds__(256) k_att1(const ushort_t* __restrict__ enc_bf,
                                              const ushort_t* __restrict__ Wenc,
                                              const float* __restrict__ benc,
                                              ushort_t* __restrict__ att1) {
    __shared__ ushort_t As[128 * 64];
    __shared__ ushort_t Bs[128 * 64];
    int tid = threadIdx.x;
    int lane = tid & 63, w = tid >> 6;
    int wr = w >> 1, wc = w & 1;
    int d = blockIdx.x;
    int lid = (d & 7) * 49 + (d >> 3);
    int by = lid >> 2, bx = lid & 3;
    int m0 = by * 128, n0 = bx * 128;
    int r16 = lane & 15;
    f32x4 acc[4][4];
    #pragma unroll
    for (int mf = 0; mf < 4; ++mf)
        #pragma unroll
        for (int nf = 0; nf < 4; ++nf) acc[mf][nf] = (f32x4){0.f, 0.f, 0.f, 0.f};

    int lrow = lane >> 3;
    int lslot = lane & 7;
    for (int k0 = 0; k0 < ENCd; k0 += 64) {
        __syncthreads();
        #pragma unroll
        for (int c = 0; c < 4; ++c) {
            int row = c * 32 + w * 8 + lrow;
            int kg = lslot ^ (row & 7);
            const ushort_t* asrc = enc_bf + (size_t)(m0 + row) * ENCd + k0 + kg * 8;
            const ushort_t* bsrc = Wenc   + (size_t)(n0 + row) * ENCd + k0 + kg * 8;
            __builtin_amdgcn_global_load_lds(
                (const __attribute__((address_space(1))) void*)asrc,
                (__attribute__((address_space(3))) void*)&As[(c * 32 + w * 8) * 64], 16, 0, 0);
            __builtin_amdgcn_global_load_lds(
                (const __attribute__((address_space(1))) void*)bsrc,
                (__attribute__((address_space(3))) void*)&Bs[(c * 32 + w * 8) * 64], 16, 0, 0);
        }
        __syncthreads();
        #pragma unroll
        for (int ks = 0; ks < 2; ++ks) {
            int sl = ks * 4 + (lane >> 4);
            short8 a[4], b[4];
            #pragma unroll
            for (int mf = 0; mf < 4; ++mf) {
                int row = wr * 64 + mf * 16 + r16;
                a[mf] = *(const short8*)&As[row * 64 + ((sl ^ (row & 7)) << 3)];
            }
            #pragma unroll
            for (int nf = 0; nf < 4; ++nf) {
                int row = wc * 64 + nf * 16 + r16;
                b[nf] = *(const short8*)&Bs[row * 64 + ((sl ^ (row & 7)) << 3)];
            }
            #pragma unroll
            for (int mf = 0; mf < 4; ++mf)
                #pragma unroll
                for (int nf = 0; nf < 4; ++nf)
                    acc[mf][nf] = MFMA16(a[mf], b[nf], acc[mf][nf], 0, 0, 0);
        }
    }
    int rj0 = (lane >> 4) << 2;
    #pragma unroll
    for (int mf = 0; mf < 4; ++mf)
        #pragma unroll
        for (int nf = 0; nf < 4; ++nf) {
            int col = n0 + wc * 64 + nf * 16 + r16;
            float bv = benc[col];
            #pragma unroll
            for (int j = 0; j < 4; ++j) {
                int row = m0 + wr * 64 + mf * 16 + rj0 + j;
                att1[(size_t)row * Aa + col] = f2b(acc[mf][nf][j] + bv);
            }
        }
}

// ---------------- h0/c0 small GEMM (split-K over 4 waves) --------------------
__global__ void __launch_bounds__(256) k_h0c0(
        const ushort_t* __restrict__ A, const ushort_t* __restrict__ W,
        const float* __restrict__ bias, ushort_t* __restrict__ hout,
        float* __restrict__ cst) {
    int lane = threadIdx.x & 63, w = threadIdx.x >> 6;
    int r16 = lane & 15, kq = (lane >> 4) << 3;
    int ncol[4];
    #pragma unroll
    for (int tt = 0; tt < 4; ++tt) ncol[tt] = blockIdx.x * 64 + tt * 16 + r16;
    f32x4 acc[4][4];
    #pragma unroll
    for (int mt = 0; mt < 4; ++mt)
        #pragma unroll
        for (int tt = 0; tt < 4; ++tt) acc[mt][tt] = (f32x4){0.f, 0.f, 0.f, 0.f};
    for (int k0 = w * 512; k0 < w * 512 + 512; k0 += 32) {
        short8 a[4];
        #pragma unroll
        for (int mt = 0; mt < 4; ++mt)
            a[mt] = *(const short8*)(A + (size_t)(mt * 16 + r16) * ENCd + k0 + kq);
        #pragma unroll
        for (int tt = 0; tt < 4; ++tt) {
            short8 bw = *(const short8*)&W[(size_t)ncol[tt] * ENCd + k0 + kq];
            #pragma unroll
            for (int mt = 0; mt < 4; ++mt)
                acc[mt][tt] = MFMA16(a[mt], bw, acc[mt][tt], 0, 0, 0);
        }
    }
    __shared__ float red[2][64][68];
    if (w >= 2) {
        float* row = &red[w - 2][lane][0];
        #pragma unroll
        for (int mt = 0; mt < 4; ++mt)
            #pragma unroll
            for (int tt = 0; tt < 4; ++tt) *(f32x4*)&row[(mt * 4 + tt) * 4] = acc[mt][tt];
    }
    __syncthreads();
    if (w < 2) {
        float* row = &red[w][lane][0];
        #pragma unroll
        for (int mt = 0; mt < 4; ++mt)
            #pragma unroll
            for (int tt = 0; tt < 4; ++tt) acc[mt][tt] += *(f32x4*)&row[(mt * 4 + tt) * 4];
    }
    __syncthreads();
    if (w == 1) {
        float* row = &red[0][lane][0];
        #pragma unroll
        for (int mt = 0; mt < 4; ++mt)
            #pragma unroll
            for (int tt = 0; tt < 4; ++tt) *(f32x4*)&row[(mt * 4 + tt) * 4] = acc[mt][tt];
    }
    __syncthreads();
    if (w != 0) return;
    {
        float* row = &red[0][lane][0];
        #pragma unroll
        for (int mt = 0; mt < 4; ++mt)
            #pragma unroll
            for (int tt = 0; tt < 4; ++tt) acc[mt][tt] += *(f32x4*)&row[(mt * 4 + tt) * 4];
    }
    int rj0 = (lane >> 4) << 2;
    #pragma unroll
    for (int mt = 0; mt < 4; ++mt)
        #pragma unroll
        for (int tt = 0; tt < 4; ++tt) {
            int col = ncol[tt];
            float bv = bias[col];
            #pragma unroll
            for (int j = 0; j < 4; ++j) {
                int row = mt * 16 + rj0 + j;
                float v = acc[mt][tt][j] + bv;
                if (col < 512) hout[row * Dd + col] = f2b(v);
                else           cst[row * Dd + (col - 512)] = v;
            }
        }
}

// ---------------- ag GEMM: [64x512] @ W_ag[2560x512]^T, 160 blocks -----------
__global__ void __launch_bounds__(256) k_ag(
        const ushort_t* __restrict__ h, const ushort_t* __restrict__ W,
        const float* __restrict__ bias, float* __restrict__ of) {
    int lane = threadIdx.x & 63, w = threadIdx.x >> 6;
    int r16 = lane & 15, kq = (lane >> 4) << 3;
    int col = blockIdx.x * 16 + r16;
    f32x4 acc[4];
    #pragma unroll
    for (int mt = 0; mt < 4; ++mt) acc[mt] = (f32x4){0.f, 0.f, 0.f, 0.f};
    for (int k0 = w * 128; k0 < w * 128 + 128; k0 += 32) {
        short8 bw = *(const short8*)&W[(size_t)col * Dd + k0 + kq];
        #pragma unroll
        for (int mt = 0; mt < 4; ++mt) {
            short8 a = *(const short8*)(h + (size_t)(mt * 16 + r16) * Dd + k0 + kq);
            acc[mt] = MFMA16(a, bw, acc[mt], 0, 0, 0);
        }
    }
    __shared__ float red[2][64][20];
    if (w >= 2) {
        float* rr = &red[w - 2][lane][0];
        #pragma unroll
        for (int mt = 0; mt < 4; ++mt) *(f32x4*)&rr[mt * 4] = acc[mt];
    }
    __syncthreads();
    if (w < 2) {
        float* rr = &red[w][lane][0];
        #pragma unroll
        for (int mt = 0; mt < 4; ++mt) acc[mt] += *(f32x4*)&rr[mt * 4];
    }
    __syncthreads();
    if (w == 1) {
        float* rr = &red[0][lane][0];
        #pragma unroll
        for (int mt = 0; mt < 4; ++mt) *(f32x4*)&rr[mt * 4] = acc[mt];
    }
    __syncthreads();
    if (w != 0) return;
    {
        float* rr = &red[0][lane][0];
        #pragma unroll
        for (int mt = 0; mt < 4; ++mt) acc[mt] += *(f32x4*)&rr[mt * 4];
    }
    int rj0 = (lane >> 4) << 2;
    float bv = bias[col];
    #pragma unroll
    for (int mt = 0; mt < 4; ++mt)
        #pragma unroll
        for (int j = 0; j < 4; ++j) {
            int row = mt * 16 + rj0 + j;
            float v = acc[mt][j] + bv;
            of[(size_t)row * K2 + col] = (col >= 512) ? fsig(v) : v;
        }
}

// ---------------- e-score + softmax (att1 read ONCE) + emb gather ------------
// grid 64 (one block per b), 1024 threads
__global__ void __launch_bounds__(1024) k_esm(
        const ushort_t* __restrict__ att1, const float* __restrict__ ag,
        const float* __restrict__ wfull, const float* __restrict__ bfull,
        const float* __restrict__ emb, const int* __restrict__ caps_s,
        float* __restrict__ alphaBuf, ushort_t* __restrict__ x2,
        float* __restrict__ out, const int* __restrict__ dlen, int t) {
    int b = blockIdx.x;
    int tid = threadIdx.x;
    int lane = tid & 63, wv = tid >> 6;
    __shared__ float att2f[512], wfl[512];
    __shared__ float e_sh[200], sm[4];
    if (tid < 512) att2f[tid] = ag[(size_t)b * K2 + tid];
    else           wfl[tid - 512] = wfull[tid - 512];
    __syncthreads();
    float a2[8], wf8[8];
    #pragma unroll
    for (int j = 0; j < 8; ++j) { a2[j] = att2f[lane * 8 + j]; wf8[j] = wfl[lane * 8 + j]; }
    float bf0 = bfull[0];
    for (int p0 = wv; p0 < Pp; p0 += 32) {
        int p1 = p0 + 16;
        bool has1 = p1 < Pp;
        short8 v0 = *(const short8*)&att1[((size_t)b * Pp + p0) * Aa + lane * 8];
        short8 v1 = has1 ? *(const short8*)&att1[((size_t)b * Pp + p1) * Aa + lane * 8] : v0;
        float s0 = 0.f, s1 = 0.f;
        #pragma unroll
        for (int j = 0; j < 8; ++j) {
            s0 += ftanh(b2f((ushort_t)v0[j]) + a2[j]) * wf8[j];
            s1 += ftanh(b2f((ushort_t)v1[j]) + a2[j]) * wf8[j];
        }
        #pragma unroll
        for (int o = 32; o; o >>= 1) {
            s0 += __shfl_xor(s0, o);
            s1 += __shfl_xor(s1, o);
        }
        if (lane == 0) {
            e_sh[p0] = s0 + bf0;
            if (has1) e_sh[p1] = s1 + bf0;
        }
    }
    __syncthreads();
    if (wv == 0) {
        float v0 = e_sh[lane];
        float v1 = e_sh[lane + 64];
        float v2 = e_sh[lane + 128];
        float v3 = (lane + 192 < Pp) ? e_sh[lane + 192] : -1e30f;
        float m = fmaxf(fmaxf(v0, v1), fmaxf(v2, v3));
        #pragma unroll
        for (int o = 32; o; o >>= 1) m = fmaxf(m, __shfl_xor(m, o));
        float ss = __expf(v0 - m) + __expf(v1 - m) + __expf(v2 - m) + __expf(v3 - m);
        #pragma unroll
        for (int o = 32; o; o >>= 1) ss += __shfl_xor(ss, o);
        if (lane == 0) { sm[0] = m; sm[1] = 1.0f / ss; }
    } else if (tid >= 512 && tid < 768) {
        int q = tid - 512;
        float2 e2v = *(const float2*)&emb[(size_t)caps_s[b * Lc + t] * Ee + q * 2];
        ushort2 o2; o2.x = f2b(e2v.x); o2.y = f2b(e2v.y);
        *(ushort2*)&x2[(size_t)b * K2 + q * 2] = o2;
    }
    __syncthreads();
    float mx = sm[0], inv = sm[1];
    if (tid < Pp) {
        float al = __expf(e_sh[tid] - mx) * inv;
        alphaBuf[b * Pp + tid] = al;
        out[OUT_ALPH + ((long long)b * Tt + t) * Pp + tid] = (t < dlen[b]) ? al : 0.0f;
    }
}

// ---------------- awe = alpha.enc ; x2[:,512:] = bf16(gate*awe) --------------
// grid 256 (4 per b, 512 cols each), 1024 threads
__global__ void __launch_bounds__(1024) k_awe(
        const float* __restrict__ alphaBuf, const ushort_t* __restrict__ enc_bf,
        const float* __restrict__ ag, ushort_t* __restrict__ x2) {
    int b = blockIdx.x >> 2, ch = blockIdx.x & 3;
    int tid = threadIdx.x;
    int cg = tid & 63, pg = tid >> 6;     // 64 col-groups x 16 p-groups
    __shared__ float al[200];
    __shared__ float redA[16][512];
    if (tid < Pp) al[tid] = alphaBuf[b * Pp + tid];
    __syncthreads();
    int c0 = cg * 8;
    float acc[8] = {};
    const ushort_t* ep = enc_bf + (size_t)b * Pp * ENCd + ch * 512 + c0;
    for (int p = pg; p < Pp; p += 16) {
        float a = al[p];
        short8 vv = *(const short8*)(ep + (size_t)p * ENCd);
        #pragma unroll
        for (int j = 0; j < 8; ++j) acc[j] += a * b2f((ushort_t)vv[j]);
    }
    *(f32x4*)&redA[pg][c0]     = *(f32x4*)&acc[0];
    *(f32x4*)&redA[pg][c0 + 4] = *(f32x4*)&acc[4];
    __syncthreads();
    if (tid < 512) {
        float s = 0.f;
        #pragma unroll
        for (int g = 0; g < 16; ++g) s += redA[g][tid];
        int col = ch * 512 + tid;
        float gte = ag[(size_t)b * K2 + 512 + col];
        x2[(size_t)b * K2 + Ee + col] = f2b(gte * s);
    }
}

// ---------------- gates GEMM + LSTM, 512 threads (8-wave split-K) ------------
__global__ void __launch_bounds__(512) k_gates(
        const ushort_t* __restrict__ x2, const ushort_t* __restrict__ hin,
        const ushort_t* __restrict__ Wcat, const float* __restrict__ bsum,
        ushort_t* __restrict__ hout, float* __restrict__ cst,
        const int* __restrict__ dlen, int t) {
    int lane = threadIdx.x & 63, w = threadIdx.x >> 6;   // 8 waves
    int r16 = lane & 15, kq = (lane >> 4) << 3;
    int m0 = blockIdx.y * 16;
    int d0 = blockIdx.x * 16;
    int row = m0 + r16;
    f32x4 acc[4];
    #pragma unroll
    for (int tt = 0; tt < 4; ++tt) acc[tt] = (f32x4){0.f, 0.f, 0.f, 0.f};
    for (int k0 = w * 384; k0 < w * 384 + 384; k0 += 32) {
        const ushort_t* s = (k0 < K2) ? (x2 + (size_t)row * K2 + k0 + kq)
                                      : (hin + (size_t)row * Dd + (k0 - K2) + kq);
        short8 a = *(const short8*)s;
        #pragma unroll
        for (int tt = 0; tt < 4; ++tt) {
            short8 bw = *(const short8*)&Wcat[(size_t)(d0 + tt * 512 + r16) * KG + k0 + kq];
            acc[tt] = MFMA16(a, bw, acc[tt], 0, 0, 0);
        }
    }
    __shared__ float red[4][64][20];
    for (int s2 = 4; s2; s2 >>= 1) {
        if (w >= s2 && w < 2 * s2) {
            float* rr = &red[w - s2][lane][0];
            #pragma unroll
            for (int tt = 0; tt < 4; ++tt) *(f32x4*)&rr[tt * 4] = acc[tt];
        }
        __syncthreads();
        if (w < s2) {
            float* rr = &red[w][lane][0];
            #pragma unroll
            for (int tt = 0; tt < 4; ++tt) acc[tt] += *(f32x4*)&rr[tt * 4];
        }
        __syncthreads();
    }
    if (w != 0) return;
    int rj0 = (lane >> 4) << 2;
    int d = d0 + r16;
    #pragma unroll
    for (int j = 0; j < 4; ++j) {
        int rw = m0 + rj0 + j;
        ushort_t hb;
        if (t < dlen[rw]) {
            float gi = acc[0][j] + bsum[d];
            float gf = acc[1][j] + bsum[512 + d];
            float gg = acc[2][j] + bsum[1024 + d];
            float go = acc[3][j] + bsum[1536 + d];
            float cv = cst[rw * Dd + d];
            float cn = fsig(gf) * cv + fsig(gi) * ftanh(gg);
            cst[rw * Dd + d] = cn;
            hb = f2b(fsig(go) * ftanh(cn));
        } else {
            hb = hin[rw * Dd + d];
        }
        hout[rw * Dd + d] = hb;
    }
}

// ---------------- batched preds: LDS-staged 128x128x64 tile GEMM -------------
__global__ void __launch_bounds__(256) k_preds(
        const ushort_t* __restrict__ hA, const ushort_t* __restrict__ Wfc,
        const float* __restrict__ bfc, const int* __restrict__ dlen,
        float* __restrict__ out) {
    __shared__ ushort_t As[128 * 64];
    __shared__ ushort_t Bs[128 * 64];
    __shared__ float wb[4][16][66];
    int tid = threadIdx.x;
    int lane = tid & 63, w = tid >> 6;
    int wr = w >> 1, wc = w & 1;
    int d = blockIdx.x;
    int x = d & 7, k = d >> 3;
    int lid = (x < 6 ? x * 99 : 594 + (x - 6) * 98) + k;
    int bx = lid / 10, by = lid % 10;
    int m0 = by * 128, n0 = bx * 128;
    int r16 = lane & 15;
    f32x4 acc[4][4];
    #pragma unroll
    for (int mf = 0; mf < 4; ++mf)
        #pragma unroll
        for (int nf = 0; nf < 4; ++nf) acc[mf][nf] = (f32x4){0.f, 0.f, 0.f, 0.f};

    int lrow = lane >> 3;
    int lslot = lane & 7;
    for (int k0 = 0; k0 < Dd; k0 += 64) {
        __syncthreads();
        #pragma unroll
        for (int c = 0; c < 4; ++c) {
            int row = c * 32 + w * 8 + lrow;
            int kg = lslot ^ (row & 7);
            const ushort_t* asrc = hA  + (size_t)(m0 + row) * Dd + k0 + kg * 8;
            const ushort_t* bsrc = Wfc + (size_t)(n0 + row) * Dd + k0 + kg * 8;
            __builtin_amdgcn_global_load_lds(
                (const __attribute__((address_space(1))) void*)asrc,
                (__attribute__((address_space(3))) void*)&As[(c * 32 + w * 8) * 64], 16, 0, 0);
            __builtin_amdgcn_global_load_lds(
                (const __attribute__((address_space(1))) void*)bsrc,
                (__attribute__((address_space(3))) void*)&Bs[(c * 32 + w * 8) * 64], 16, 0, 0);
        }
        __syncthreads();
        #pragma unroll
        for (int ks = 0; ks < 2; ++ks) {
            int sl = ks * 4 + (lane >> 4);
            short8 a[4], b[4];
            #pragma unroll
            for (int mf = 0; mf < 4; ++mf) {
                int row = wr * 64 + mf * 16 + r16;
                a[mf] = *(const short8*)&As[row * 64 + ((sl ^ (row & 7)) << 3)];
            }
            #pragma unroll
            for (int nf = 0; nf < 4; ++nf) {
                int row = wc * 64 + nf * 16 + r16;
                b[nf] = *(const short8*)&Bs[row * 64 + ((sl ^ (row & 7)) << 3)];
            }
            #pragma unroll
            for (int mf = 0; mf < 4; ++mf)
                #pragma unroll
                for (int nf = 0; nf < 4; ++nf)
                    acc[mf][nf] = MFMA16(a[mf], b[nf], acc[mf][nf], 0, 0, 0);
        }
    }
    int rj0 = (lane >> 4) << 2;
    #pragma unroll
    for (int mf = 0; mf < 4; ++mf) {
        #pragma unroll
        for (int nf = 0; nf < 4; ++nf) {
            float bv = bfc[n0 + wc * 64 + nf * 16 + r16];
            #pragma unroll
            for (int j = 0; j < 4; ++j)
                wb[w][rj0 + j][nf * 16 + r16] = acc[mf][nf][j] + bv;
        }
        asm volatile("s_waitcnt lgkmcnt(0)" ::: "memory");
        #pragma unroll
        for (int c = 0; c < 4; ++c) {
            int idx = c * 64 + lane;
            int row16 = idx >> 4, c4 = idx & 15;
            int grow = m0 + wr * 64 + mf * 16 + row16;
            int gcol = n0 + wc * 64 + c4 * 4;
            if (grow < 1216 && gcol < Vv) {
                int ts = grow >> 6, b = grow & 63;
                f32x4 v = *(f32x4*)&wb[w][row16][c4 * 4];
                if (ts >= dlen[b]) v = (f32x4){0.f, 0.f, 0.f, 0.f};
                __builtin_nontemporal_store(v,
                    (f32x4*)&out[OUT_PRED + ((long long)b * Tt + ts) * Vv + gcol]);
            }
        }
        asm volatile("s_waitcnt vmcnt(0)" ::: "memory");
    }
}

extern "C" void kernel_launch(void* const* d_in, const int* in_sizes, int n_in,
                              void* d_out, int out_size, void* d_ws, size_t ws_size,
                              hipStream_t stream) {
    const float* encoder_out      = (const float*)d_in[0];
    const int*   encoded_captions = (const int*)d_in[1];
    const int*   caption_lengths  = (const int*)d_in[2];
    const float* emb       = (const float*)d_in[3];
    const float* W_ih      = (const float*)d_in[4];
    const float* b_ih      = (const float*)d_in[5];
    const float* W_hh      = (const float*)d_in[6];
    const float* b_hh      = (const float*)d_in[7];
    const float* W_init_h  = (const float*)d_in[8];
    const float* b_init_h  = (const float*)d_in[9];
    const float* W_init_c  = (const float*)d_in[10];
    const float* b_init_c  = (const float*)d_in[11];
    const float* W_fbeta   = (const float*)d_in[12];
    const float* b_fbeta   = (const float*)d_in[13];
    const float* W_fc      = (const float*)d_in[14];
    const float* b_fc      = (const float*)d_in[15];
    const float* W_enc_att = (const float*)d_in[16];
    const float* b_enc_att = (const float*)d_in[17];
    const float* W_dec_att = (const float*)d_in[18];
    const float* b_dec_att = (const float*)d_in[19];
    const float* W_full_att = (const float*)d_in[20];
    const float* b_full_att = (const float*)d_in[21];
    float* out = (float*)d_out;

    char* p = (char*)d_ws;
    auto alloc = [&](size_t bytes) { char* r = p; p += (bytes + 255) & ~255ull; return r; };
    int* sind   = (int*)alloc(64 * 4);
    int* dlen   = (int*)alloc(64 * 4);
    int* caps_s = (int*)alloc(Bb * Lc * 4);
    float* c_st     = (float*)alloc(Bb * Dd * 4);
    float* ag       = (float*)alloc((size_t)Bb * K2 * 4);
    float* alphaBuf = (float*)alloc(Bb * Pp * 4);
    float* b_ag  = (float*)alloc(K2 * 4);
    float* bsum  = (float*)alloc(G4 * 4);
    float* b_hc  = (float*)alloc(1024 * 4);
    ushort_t* mean_bf = (ushort_t*)alloc((size_t)Bb * ENCd * 2);
    ushort_t* hball   = (ushort_t*)alloc((size_t)(Tt + 2) * Bb * Dd * 2);
    ushort_t* x2      = (ushort_t*)alloc((size_t)Bb * K2 * 2);
    ushort_t* att1    = (ushort_t*)alloc((size_t)Bb * Pp * Aa * 2);
    ushort_t* W_enc   = (ushort_t*)alloc((size_t)Aa * ENCd * 2);
    ushort_t* W_ag    = (ushort_t*)alloc((size_t)K2 * Dd * 2);
    ushort_t* W_cat   = (ushort_t*)alloc((size_t)G4 * KG * 2);
    ushort_t* W_fcb   = (ushort_t*)alloc((size_t)NPAD * Dd * 2);
    ushort_t* W_hcb   = (ushort_t*)alloc((size_t)1024 * ENCd * 2);
    ushort_t* enc_bf  = (ushort_t*)alloc((size_t)Bb * Pp * ENCd * 2);

    k_sort<<<1, 64, 0, stream>>>(caption_lengths, encoded_captions, out, sind, dlen, caps_s);
    k_cvtall<<<15496, 256, 0, stream>>>(W_dec_att, W_fbeta, W_ih, W_hh, W_fc, W_enc_att,
                                        W_init_h, W_init_c, W_ag, W_cat, W_fcb, W_enc, W_hcb);
    k_bias<<<10, 256, 0, stream>>>(b_dec_att, b_fbeta, b_ih, b_hh, b_init_h, b_init_c,
                                   b_ag, bsum, b_hc);
    k_enccvt<<<2048, 256, 0, stream>>>(encoder_out, sind, enc_bf);
    k_meanenc<<<64, 1024, 0, stream>>>(enc_bf, mean_bf);
    k_h0c0<<<16, 256, 0, stream>>>(mean_bf, W_hcb, b_hc, hball, c_st);
    k_att1<<<392, 256, 0, stream>>>(enc_bf, W_enc, b_enc_att, att1);

    for (int t = 0; t < Tt; ++t) {
        const ushort_t* hcur = hball + (size_t)t * Bb * Dd;
        ushort_t* hnext = hball + (size_t)(t + 1) * Bb * Dd;
        k_ag<<<160, 256, 0, stream>>>(hcur, W_ag, b_ag, ag);
        k_esm<<<64, 1024, 0, stream>>>(att1, ag, W_full_att, b_full_att,
            emb, caps_s, alphaBuf, x2, out, dlen, t);
        k_awe<<<256, 1024, 0, stream>>>(alphaBuf, enc_bf, ag, x2);
        k_gates<<<dim3(32, 4), 512, 0, stream>>>(x2, hcur, W_cat, bsum, hnext, c_st, dlen, t);
    }
    k_preds<<<790, 256, 0, stream>>>(hball + (size_t)Bb * Dd, W_fcb, b_fc, dlen, out);
}

// Round 15
// 1149.455 us; speedup vs baseline: 1.4096x; 1.0321x over previous
//
#include <hip/hip_runtime.h>
#include <math.h>

#define Bb 64
#define Pp 196
#define ENCd 2048
#define Lc 20
#define Tt 19
#define Vv 10000
#define Ee 512
#define Dd 512
#define Aa 512
#define K2 2560     // E + ENC  (x2 = [emb, gate*awe])
#define KG 3072     // E + ENC + D
#define G4 2048     // 4*D
#define NPAD 10112  // Vv padded to 79*128

#define OUT_PRED 0ll
#define OUT_CAPS 12160000ll   // B*T*V
#define OUT_ALPH 12161280ll   // + B*L
#define OUT_SIND 12399616ll   // + B*T*P

typedef unsigned short ushort_t;
typedef __attribute__((ext_vector_type(8))) short short8;
typedef __attribute__((ext_vector_type(4))) float f32x4;

#define MFMA16 __builtin_amdgcn_mfma_f32_16x16x32_bf16

__device__ __forceinline__ float b2f(ushort_t u) {
    union { unsigned int i; float f; } x; x.i = ((unsigned int)u) << 16; return x.f;
}
__device__ __forceinline__ ushort_t f2b(float f) {
    union { float f; unsigned int i; } x; x.f = f;
    unsigned int r = x.i + 0x7fffu + ((x.i >> 16) & 1u);
    return (ushort_t)(r >> 16);
}
__device__ __forceinline__ float fsig(float x) { return 1.0f / (1.0f + __expf(-x)); }
__device__ __forceinline__ float ftanh(float x) {
    x = fminf(fmaxf(x, -15.0f), 15.0f);
    float e = __expf(2.0f * x);
    return (e - 1.0f) / (e + 1.0f);
}

// ---------------- sort (stable descending argsort of caption lengths) --------
__global__ void k_sort(const int* __restrict__ cap_len, const int* __restrict__ caps_in,
                       float* __restrict__ out, int* __restrict__ sind,
                       int* __restrict__ dlen, int* __restrict__ caps_s) {
    __shared__ int cls[Bb];
    int i = threadIdx.x;
    int cl = cap_len[i];
    cls[i] = cl;
    __syncthreads();
    int rank = 0;
    for (int j = 0; j < Bb; ++j) {
        int cj = cls[j];
        rank += (cj > cl) || (cj == cl && j < i);
    }
    sind[rank] = i;
    dlen[rank] = cl - 1;
    out[OUT_SIND + rank] = (float)i;
    for (int l = 0; l < Lc; ++l) {
        int v = caps_in[i * Lc + l];
        caps_s[rank * Lc + l] = v;
        out[OUT_CAPS + rank * Lc + l] = (float)v;
    }
}

// ---------------- precompute all emb gathers: x2all[t][b][:512] --------------
__global__ void __launch_bounds__(256) k_emball(const float* __restrict__ emb,
                                                const int* __restrict__ caps_s,
                                                ushort_t* __restrict__ x2all) {
    int blk = blockIdx.x;            // 1216 = 19*64
    int t = blk / Bb, b = blk % Bb;
    int q = threadIdx.x;             // 256 threads x 2 elems
    float2 e2v = *(const float2*)&emb[(size_t)caps_s[b * Lc + t] * Ee + q * 2];
    ushort2 o2; o2.x = f2b(e2v.x); o2.y = f2b(e2v.y);
    *(ushort2*)&x2all[((size_t)t * Bb + b) * K2 + q * 2] = o2;
}

// ---------------- merged weight conversions ----------------------------------
__device__ __forceinline__ void cvtseg(const float* __restrict__ src, ushort_t* __restrict__ dst,
                                       int cols, int stride, int off, int bid0, long long quads) {
    long long qid = (long long)bid0 * 256 + threadIdx.x;
    if (qid >= quads) return;
    int c4pr = cols >> 2;
    int r = (int)(qid / c4pr), c4 = (int)(qid % c4pr) << 2;
    float4 v = *(const float4*)&src[(size_t)r * cols + c4];
    ushort4 o; o.x = f2b(v.x); o.y = f2b(v.y); o.z = f2b(v.z); o.w = f2b(v.w);
    *(ushort4*)&dst[(size_t)r * stride + off + c4] = o;
}

__global__ void k_cvtall(const float* Wdec, const float* Wfb, const float* Wih,
                         const float* Whh, const float* Wfc, const float* Wenc_f,
                         const float* Wih0, const float* Wic0,
                         ushort_t* W_ag, ushort_t* W_cat, ushort_t* W_fcb,
                         ushort_t* W_enc, ushort_t* W_hcb) {
    int b = blockIdx.x;
    if      (b < 256)   cvtseg(Wdec,  W_ag,               512,  512,  0,    b,         65536);
    else if (b < 1280)  cvtseg(Wfb,   W_ag + 512 * 512,   512,  512,  0,    b - 256,   262144);
    else if (b < 6400)  cvtseg(Wih,   W_cat,              2560, 3072, 0,    b - 1280,  1310720);
    else if (b < 7424)  cvtseg(Whh,   W_cat,              512,  3072, 2560, b - 6400,  262144);
    else if (b < 12424) cvtseg(Wfc,   W_fcb,              512,  512,  0,    b - 7424,  1280000);
    else if (b < 13448) cvtseg(Wenc_f,W_enc,              2048, 2048, 0,    b - 12424, 262144);
    else if (b < 14472) cvtseg(Wih0,  W_hcb,              2048, 2048, 0,    b - 13448, 262144);
    else                cvtseg(Wic0,  W_hcb + 512 * 2048, 2048, 2048, 0,    b - 14472, 262144);
}

// ---------------- bias prep --------------------------------------------------
__global__ void k_bias(const float* b_dec, const float* b_fb, const float* b_ihp,
                       const float* b_hhp, const float* b_h, const float* b_c,
                       float* b_ag, float* bsum, float* b_hc) {
    int id = blockIdx.x * 256 + threadIdx.x;
    if (id < 512) b_ag[id] = b_dec[id];
    else if (id < 2560) b_ag[id] = b_fb[id - 512];
    if (id < 2048) bsum[id] = b_ihp[id] + b_hhp[id];
    if (id < 512) b_hc[id] = b_h[id];
    else if (id < 1024) b_hc[id] = b_c[id - 512];
}

// ---------------- gather+convert encoder_out (sorted) -> bf16 ----------------
__global__ void __launch_bounds__(256) k_enccvt(const float* __restrict__ enc,
                                                const int* __restrict__ sind,
                                                ushort_t* __restrict__ enc_bf) {
    const long long total8 = (long long)Bb * Pp * ENCd / 8;
    for (long long u = (long long)blockIdx.x * 256 + threadIdx.x; u < total8;
         u += (long long)gridDim.x * 256) {
        long long flat = u * 8;
        int r = (int)(flat >> 11);
        int c8 = (int)(flat & 2047);
        int b = r / Pp;
        size_t srow = (size_t)sind[b] * Pp + (r - b * Pp);
        const float* s = enc + srow * ENCd + c8;
        float4 v0 = *(const float4*)s;
        float4 v1 = *(const float4*)(s + 4);
        short8 o;
        o[0] = (short)f2b(v0.x); o[1] = (short)f2b(v0.y); o[2] = (short)f2b(v0.z); o[3] = (short)f2b(v0.w);
        o[4] = (short)f2b(v1.x); o[5] = (short)f2b(v1.y); o[6] = (short)f2b(v1.z); o[7] = (short)f2b(v1.w);
        *(short8*)&enc_bf[(size_t)r * ENCd + c8] = o;
    }
}

// ---------------- mean over pixels (from bf16) -------------------------------
__global__ void __launch_bounds__(1024) k_meanenc(const ushort_t* __restrict__ enc_bf,
                                                  ushort_t* __restrict__ mean_bf) {
    int b = blockIdx.x;
    int lane = threadIdx.x & 63, w = threadIdx.x >> 6;
    int cg = w & 3, pg = w >> 2;
    int lc = cg * 512 + lane * 8;
    __shared__ float red[4][2048];
    float acc[8] = {};
    for (int p = pg; p < Pp; p += 4) {
        short8 v = *(const short8*)&enc_bf[((size_t)b * Pp + p) * ENCd + lc];
        #pragma unroll
        for (int j = 0; j < 8; ++j) acc[j] += b2f((ushort_t)v[j]);
    }
    #pragma unroll
    for (int j = 0; j < 8; ++j) red[pg][lc + j] = acc[j];
    __syncthreads();
    int tid = threadIdx.x;
    float2 s = {0.f, 0.f};
    #pragma unroll
    for (int g = 0; g < 4; ++g) {
        float2 v = *(const float2*)&red[g][tid * 2];
        s.x += v.x; s.y += v.y;
    }
    ushort2 o; o.x = f2b(s.x * (1.0f / Pp)); o.y = f2b(s.y * (1.0f / Pp));
    *(ushort2*)&mean_bf[(size_t)b * ENCd + tid * 2] = o;
}

// ---------------- att1: LDS-staged 128x128x64 tile GEMM, XCD-swizzled --------
__global__ void __launch_bounds__(256) k_att1(const ushort_t* __restrict__ enc_bf,
                                              const ushort_t* __restrict__ Wenc,
                                              const float* __restrict__ benc,
                                              ushort_t* __restrict__ att1) {
    __shared__ ushort_t As[128 * 64];
    __shared__ ushort_t Bs[128 * 64];
    int tid = threadIdx.x;
    int lane = tid & 63, w = tid >> 6;
    int wr = w >> 1, wc = w & 1;
    int d = blockIdx.x;
    int lid = (d & 7) * 49 + (d >> 3);
    int by = lid >> 2, bx = lid & 3;
    int m0 = by * 128, n0 = bx * 128;
    int r16 = lane & 15;
    f32x4 acc[4][4];
    #pragma unroll
    for (int mf = 0; mf < 4; ++mf)
        #pragma unroll
        for (int nf = 0; nf < 4; ++nf) acc[mf][nf] = (f32x4){0.f, 0.f, 0.f, 0.f};

    int lrow = lane >> 3;
    int lslot = lane & 7;
    for (int k0 = 0; k0 < ENCd; k0 += 64) {
        __syncthreads();
        #pragma unroll
        for (int c = 0; c < 4; ++c) {
            int row = c * 32 + w * 8 + lrow;
            int kg = lslot ^ (row & 7);
            const ushort_t* asrc = enc_bf + (size_t)(m0 + row) * ENCd + k0 + kg * 8;
            const ushort_t* bsrc = Wenc   + (size_t)(n0 + row) * ENCd + k0 + kg * 8;
            __builtin_amdgcn_global_load_lds(
                (const __attribute__((address_space(1))) void*)asrc,
                (__attribute__((address_space(3))) void*)&As[(c * 32 + w * 8) * 64], 16, 0, 0);
            __builtin_amdgcn_global_load_lds(
                (const __attribute__((address_space(1))) void*)bsrc,
                (__attribute__((address_space(3))) void*)&Bs[(c * 32 + w * 8) * 64], 16, 0, 0);
        }
        __syncthreads();
        #pragma unroll
        for (int ks = 0; ks < 2; ++ks) {
            int sl = ks * 4 + (lane >> 4);
            short8 a[4], b[4];
            #pragma unroll
            for (int mf = 0; mf < 4; ++mf) {
                int row = wr * 64 + mf * 16 + r16;
                a[mf] = *(const short8*)&As[row * 64 + ((sl ^ (row & 7)) << 3)];
            }
            #pragma unroll
            for (int nf = 0; nf < 4; ++nf) {
                int row = wc * 64 + nf * 16 + r16;
                b[nf] = *(const short8*)&Bs[row * 64 + ((sl ^ (row & 7)) << 3)];
            }
            #pragma unroll
            for (int mf = 0; mf < 4; ++mf)
                #pragma unroll
                for (int nf = 0; nf < 4; ++nf)
                    acc[mf][nf] = MFMA16(a[mf], b[nf], acc[mf][nf], 0, 0, 0);
        }
    }
    int rj0 = (lane >> 4) << 2;
    #pragma unroll
    for (int mf = 0; mf < 4; ++mf)
        #pragma unroll
        for (int nf = 0; nf < 4; ++nf) {
            int col = n0 + wc * 64 + nf * 16 + r16;
            float bv = benc[col];
            #pragma unroll
            for (int j = 0; j < 4; ++j) {
                int row = m0 + wr * 64 + mf * 16 + rj0 + j;
                att1[(size_t)row * Aa + col] = f2b(acc[mf][nf][j] + bv);
            }
        }
}

// ---------------- h0/c0 small GEMM (split-K over 4 waves) --------------------
__global__ void __launch_bounds__(256) k_h0c0(
        const ushort_t* __restrict__ A, const ushort_t* __restrict__ W,
        const float* __restrict__ bias, ushort_t* __restrict__ hout,
        float* __restrict__ cst) {
    int lane = threadIdx.x & 63, w = threadIdx.x >> 6;
    int r16 = lane & 15, kq = (lane >> 4) << 3;
    int ncol[4];
    #pragma unroll
    for (int tt = 0; tt < 4; ++tt) ncol[tt] = blockIdx.x * 64 + tt * 16 + r16;
    f32x4 acc[4][4];
    #pragma unroll
    for (int mt = 0; mt < 4; ++mt)
        #pragma unroll
        for (int tt = 0; tt < 4; ++tt) acc[mt][tt] = (f32x4){0.f, 0.f, 0.f, 0.f};
    for (int k0 = w * 512; k0 < w * 512 + 512; k0 += 32) {
        short8 a[4];
        #pragma unroll
        for (int mt = 0; mt < 4; ++mt)
            a[mt] = *(const short8*)(A + (size_t)(mt * 16 + r16) * ENCd + k0 + kq);
        #pragma unroll
        for (int tt = 0; tt < 4; ++tt) {
            short8 bw = *(const short8*)&W[(size_t)ncol[tt] * ENCd + k0 + kq];
            #pragma unroll
            for (int mt = 0; mt < 4; ++mt)
                acc[mt][tt] = MFMA16(a[mt], bw, acc[mt][tt], 0, 0, 0);
        }
    }
    __shared__ float red[2][64][68];
    if (w >= 2) {
        float* row = &red[w - 2][lane][0];
        #pragma unroll
        for (int mt = 0; mt < 4; ++mt)
            #pragma unroll
            for (int tt = 0; tt < 4; ++tt) *(f32x4*)&row[(mt * 4 + tt) * 4] = acc[mt][tt];
    }
    __syncthreads();
    if (w < 2) {
        float* row = &red[w][lane][0];
        #pragma unroll
        for (int mt = 0; mt < 4; ++mt)
            #pragma unroll
            for (int tt = 0; tt < 4; ++tt) acc[mt][tt] += *(f32x4*)&row[(mt * 4 + tt) * 4];
    }
    __syncthreads();
    if (w == 1) {
        float* row = &red[0][lane][0];
        #pragma unroll
        for (int mt = 0; mt < 4; ++mt)
            #pragma unroll
            for (int tt = 0; tt < 4; ++tt) *(f32x4*)&row[(mt * 4 + tt) * 4] = acc[mt][tt];
    }
    __syncthreads();
    if (w != 0) return;
    {
        float* row = &red[0][lane][0];
        #pragma unroll
        for (int mt = 0; mt < 4; ++mt)
            #pragma unroll
            for (int tt = 0; tt < 4; ++tt) acc[mt][tt] += *(f32x4*)&row[(mt * 4 + tt) * 4];
    }
    int rj0 = (lane >> 4) << 2;
    #pragma unroll
    for (int mt = 0; mt < 4; ++mt)
        #pragma unroll
        for (int tt = 0; tt < 4; ++tt) {
            int col = ncol[tt];
            float bv = bias[col];
            #pragma unroll
            for (int j = 0; j < 4; ++j) {
                int row = mt * 16 + rj0 + j;
                float v = acc[mt][tt][j] + bv;
                if (col < 512) hout[row * Dd + col] = f2b(v);
                else           cst[row * Dd + (col - 512)] = v;
            }
        }
}

// ---------------- ag GEMM: [64x512] @ W_ag[2560x512]^T, 160 blocks -----------
__global__ void __launch_bounds__(256) k_ag(
        const ushort_t* __restrict__ h, const ushort_t* __restrict__ W,
        const float* __restrict__ bias, float* __restrict__ of) {
    int lane = threadIdx.x & 63, w = threadIdx.x >> 6;
    int r16 = lane & 15, kq = (lane >> 4) << 3;
    int col = blockIdx.x * 16 + r16;
    f32x4 acc[4];
    #pragma unroll
    for (int mt = 0; mt < 4; ++mt) acc[mt] = (f32x4){0.f, 0.f, 0.f, 0.f};
    for (int k0 = w * 128; k0 < w * 128 + 128; k0 += 32) {
        short8 bw = *(const short8*)&W[(size_t)col * Dd + k0 + kq];
        #pragma unroll
        for (int mt = 0; mt < 4; ++mt) {
            short8 a = *(const short8*)(h + (size_t)(mt * 16 + r16) * Dd + k0 + kq);
            acc[mt] = MFMA16(a, bw, acc[mt], 0, 0, 0);
        }
    }
    __shared__ float red[2][64][20];
    if (w >= 2) {
        float* rr = &red[w - 2][lane][0];
        #pragma unroll
        for (int mt = 0; mt < 4; ++mt) *(f32x4*)&rr[mt * 4] = acc[mt];
    }
    __syncthreads();
    if (w < 2) {
        float* rr = &red[w][lane][0];
        #pragma unroll
        for (int mt = 0; mt < 4; ++mt) acc[mt] += *(f32x4*)&rr[mt * 4];
    }
    __syncthreads();
    if (w == 1) {
        float* rr = &red[0][lane][0];
        #pragma unroll
        for (int mt = 0; mt < 4; ++mt) *(f32x4*)&rr[mt * 4] = acc[mt];
    }
    __syncthreads();
    if (w != 0) return;
    {
        float* rr = &red[0][lane][0];
        #pragma unroll
        for (int mt = 0; mt < 4; ++mt) acc[mt] += *(f32x4*)&rr[mt * 4];
    }
    int rj0 = (lane >> 4) << 2;
    float bv = bias[col];
    #pragma unroll
    for (int mt = 0; mt < 4; ++mt)
        #pragma unroll
        for (int j = 0; j < 4; ++j) {
            int row = mt * 16 + rj0 + j;
            float v = acc[mt][j] + bv;
            of[(size_t)row * K2 + col] = (col >= 512) ? fsig(v) : v;
        }
}

// ---------------- fused e-score + softmax + awe (4 blocks per b) -------------
// grid 256: block (b = bid>>2, ch = bid&3). e-score/softmax redundant per block;
// awe handles cols [ch*512, ch*512+512). ch==0 also writes masked alpha out.
__global__ void __launch_bounds__(1024) k_esmawe(
        const ushort_t* __restrict__ att1, const float* __restrict__ ag,
        const float* __restrict__ wfull, const float* __restrict__ bfull,
        const ushort_t* __restrict__ enc_bf,
        ushort_t* __restrict__ x2, float* __restrict__ out,
        const int* __restrict__ dlen, int t) {
    int b = blockIdx.x >> 2, ch = blockIdx.x & 3;
    int tid = threadIdx.x;
    int lane = tid & 63, wv = tid >> 6;
    __shared__ float att2f[512], wfl[512];
    __shared__ float e_sh[200], al_sh[200], sm[4];
    __shared__ float redA[16][512];
    if (tid < 512) att2f[tid] = ag[(size_t)b * K2 + tid];
    else           wfl[tid - 512] = wfull[tid - 512];
    __syncthreads();
    // e-scores, 2-way p unroll
    float a2[8], wf8[8];
    #pragma unroll
    for (int j = 0; j < 8; ++j) { a2[j] = att2f[lane * 8 + j]; wf8[j] = wfl[lane * 8 + j]; }
    float bf0 = bfull[0];
    for (int p0 = wv; p0 < Pp; p0 += 32) {
        int p1 = p0 + 16;
        bool has1 = p1 < Pp;
        short8 v0 = *(const short8*)&att1[((size_t)b * Pp + p0) * Aa + lane * 8];
        short8 v1 = has1 ? *(const short8*)&att1[((size_t)b * Pp + p1) * Aa + lane * 8] : v0;
        float s0 = 0.f, s1 = 0.f;
        #pragma unroll
        for (int j = 0; j < 8; ++j) {
            s0 += ftanh(b2f((ushort_t)v0[j]) + a2[j]) * wf8[j];
            s1 += ftanh(b2f((ushort_t)v1[j]) + a2[j]) * wf8[j];
        }
        #pragma unroll
        for (int o = 32; o; o >>= 1) {
            s0 += __shfl_xor(s0, o);
            s1 += __shfl_xor(s1, o);
        }
        if (lane == 0) {
            e_sh[p0] = s0 + bf0;
            if (has1) e_sh[p1] = s1 + bf0;
        }
    }
    __syncthreads();
    // wave-0 softmax reduce (2 syncs total)
    if (wv == 0) {
        float v0 = e_sh[lane];
        float v1 = e_sh[lane + 64];
        float v2 = e_sh[lane + 128];
        float v3 = (lane + 192 < Pp) ? e_sh[lane + 192] : -1e30f;
        float m = fmaxf(fmaxf(v0, v1), fmaxf(v2, v3));
        #pragma unroll
        for (int o = 32; o; o >>= 1) m = fmaxf(m, __shfl_xor(m, o));
        float ss = __expf(v0 - m) + __expf(v1 - m) + __expf(v2 - m) + __expf(v3 - m);
        #pragma unroll
        for (int o = 32; o; o >>= 1) ss += __shfl_xor(ss, o);
        if (lane == 0) { sm[0] = m; sm[1] = 1.0f / ss; }
    }
    __syncthreads();
    float mx = sm[0], inv = sm[1];
    if (tid < Pp) {
        float al = __expf(e_sh[tid] - mx) * inv;
        al_sh[tid] = al;
        if (ch == 0)
            out[OUT_ALPH + ((long long)b * Tt + t) * Pp + tid] = (t < dlen[b]) ? al : 0.0f;
    }
    __syncthreads();
    // awe over this block's 512 cols: 64 col-groups (8 cols) x 16 p-groups
    {
        int cg = tid & 63, pg = tid >> 6;
        int c0 = cg * 8;
        float acc[8] = {};
        const ushort_t* ep = enc_bf + (size_t)b * Pp * ENCd + ch * 512 + c0;
        for (int p = pg; p < Pp; p += 16) {
            float a = al_sh[p];
            short8 vv = *(const short8*)(ep + (size_t)p * ENCd);
            #pragma unroll
            for (int j = 0; j < 8; ++j) acc[j] += a * b2f((ushort_t)vv[j]);
        }
        *(f32x4*)&redA[pg][c0]     = *(f32x4*)&acc[0];
        *(f32x4*)&redA[pg][c0 + 4] = *(f32x4*)&acc[4];
    }
    __syncthreads();
    if (tid < 512) {
        float s = 0.f;
        #pragma unroll
        for (int g = 0; g < 16; ++g) s += redA[g][tid];
        int col = ch * 512 + tid;
        float gte = ag[(size_t)b * K2 + 512 + col];
        x2[(size_t)b * K2 + Ee + col] = f2b(gte * s);
    }
}

// ---------------- gates GEMM + LSTM, 512 threads (8-wave split-K) ------------
__global__ void __launch_bounds__(512) k_gates(
        const ushort_t* __restrict__ x2, const ushort_t* __restrict__ hin,
        const ushort_t* __restrict__ Wcat, const float* __restrict__ bsum,
        ushort_t* __restrict__ hout, float* __restrict__ cst,
        const int* __restrict__ dlen, int t) {
    int lane = threadIdx.x & 63, w = threadIdx.x >> 6;   // 8 waves
    int r16 = lane & 15, kq = (lane >> 4) << 3;
    int m0 = blockIdx.y * 16;
    int d0 = blockIdx.x * 16;
    int row = m0 + r16;
    f32x4 acc[4];
    #pragma unroll
    for (int tt = 0; tt < 4; ++tt) acc[tt] = (f32x4){0.f, 0.f, 0.f, 0.f};
    for (int k0 = w * 384; k0 < w * 384 + 384; k0 += 32) {
        const ushort_t* s = (k0 < K2) ? (x2 + (size_t)row * K2 + k0 + kq)
                                      : (hin + (size_t)row * Dd + (k0 - K2) + kq);
        short8 a = *(const short8*)s;
        #pragma unroll
        for (int tt = 0; tt < 4; ++tt) {
            short8 bw = *(const short8*)&Wcat[(size_t)(d0 + tt * 512 + r16) * KG + k0 + kq];
            acc[tt] = MFMA16(a, bw, acc[tt], 0, 0, 0);
        }
    }
    __shared__ float red[4][64][20];
    for (int s2 = 4; s2; s2 >>= 1) {
        if (w >= s2 && w < 2 * s2) {
            float* rr = &red[w - s2][lane][0];
            #pragma unroll
            for (int tt = 0; tt < 4; ++tt) *(f32x4*)&rr[tt * 4] = acc[tt];
        }
        __syncthreads();
        if (w < s2) {
            float* rr = &red[w][lane][0];
            #pragma unroll
            for (int tt = 0; tt < 4; ++tt) acc[tt] += *(f32x4*)&rr[tt * 4];
        }
        __syncthreads();
    }
    if (w != 0) return;
    int rj0 = (lane >> 4) << 2;
    int d = d0 + r16;
    #pragma unroll
    for (int j = 0; j < 4; ++j) {
        int rw = m0 + rj0 + j;
        ushort_t hb;
        if (t < dlen[rw]) {
            float gi = acc[0][j] + bsum[d];
            float gf = acc[1][j] + bsum[512 + d];
            float gg = acc[2][j] + bsum[1024 + d];
            float go = acc[3][j] + bsum[1536 + d];
            float cv = cst[rw * Dd + d];
            float cn = fsig(gf) * cv + fsig(gi) * ftanh(gg);
            cst[rw * Dd + d] = cn;
            hb = f2b(fsig(go) * ftanh(cn));
        } else {
            hb = hin[rw * Dd + d];
        }
        hout[rw * Dd + d] = hb;
    }
}

// ---------------- batched preds: LDS-staged 128x128x64 tile GEMM -------------
__global__ void __launch_bounds__(256) k_preds(
        const ushort_t* __restrict__ hA, const ushort_t* __restrict__ Wfc,
        const float* __restrict__ bfc, const int* __restrict__ dlen,
        float* __restrict__ out) {
    __shared__ ushort_t As[128 * 64];
    __shared__ ushort_t Bs[128 * 64];
    __shared__ float wb[4][16][66];
    int tid = threadIdx.x;
    int lane = tid & 63, w = tid >> 6;
    int wr = w >> 1, wc = w & 1;
    int d = blockIdx.x;
    int x = d & 7, k = d >> 3;
    int lid = (x < 6 ? x * 99 : 594 + (x - 6) * 98) + k;
    int bx = lid / 10, by = lid % 10;
    int m0 = by * 128, n0 = bx * 128;
    int r16 = lane & 15;
    f32x4 acc[4][4];
    #pragma unroll
    for (int mf = 0; mf < 4; ++mf)
        #pragma unroll
        for (int nf = 0; nf < 4; ++nf) acc[mf][nf] = (f32x4){0.f, 0.f, 0.f, 0.f};

    int lrow = lane >> 3;
    int lslot = lane & 7;
    for (int k0 = 0; k0 < Dd; k0 += 64) {
        __syncthreads();
        #pragma unroll
        for (int c = 0; c < 4; ++c) {
            int row = c * 32 + w * 8 + lrow;
            int kg = lslot ^ (row & 7);
            const ushort_t* asrc = hA  + (size_t)(m0 + row) * Dd + k0 + kg * 8;
            const ushort_t* bsrc = Wfc + (size_t)(n0 + row) * Dd + k0 + kg * 8;
            __builtin_amdgcn_global_load_lds(
                (const __attribute__((address_space(1))) void*)asrc,
                (__attribute__((address_space(3))) void*)&As[(c * 32 + w * 8) * 64], 16, 0, 0);
            __builtin_amdgcn_global_load_lds(
                (const __attribute__((address_space(1))) void*)bsrc,
                (__attribute__((address_space(3))) void*)&Bs[(c * 32 + w * 8) * 64], 16, 0, 0);
        }
        __syncthreads();
        #pragma unroll
        for (int ks = 0; ks < 2; ++ks) {
            int sl = ks * 4 + (lane >> 4);
            short8 a[4], b[4];
            #pragma unroll
            for (int mf = 0; mf < 4; ++mf) {
                int row = wr * 64 + mf * 16 + r16;
                a[mf] = *(const short8*)&As[row * 64 + ((sl ^ (row & 7)) << 3)];
            }
            #pragma unroll
            for (int nf = 0; nf < 4; ++nf) {
                int row = wc * 64 + nf * 16 + r16;
                b[nf] = *(const short8*)&Bs[row * 64 + ((sl ^ (row & 7)) << 3)];
            }
            #pragma unroll
            for (int mf = 0; mf < 4; ++mf)
                #pragma unroll
                for (int nf = 0; nf < 4; ++nf)
                    acc[mf][nf] = MFMA16(a[mf], b[nf], acc[mf][nf], 0, 0, 0);
        }
    }
    int rj0 = (lane >> 4) << 2;
    #pragma unroll
    for (int mf = 0; mf < 4; ++mf) {
        #pragma unroll
        for (int nf = 0; nf < 4; ++nf) {
            float bv = bfc[n0 + wc * 64 + nf * 16 + r16];
            #pragma unroll
            for (int j = 0; j < 4; ++j)
                wb[w][rj0 + j][nf * 16 + r16] = acc[mf][nf][j] + bv;
        }
        asm volatile("s_waitcnt lgkmcnt(0)" ::: "memory");
        #pragma unroll
        for (int c = 0; c < 4; ++c) {
            int idx = c * 64 + lane;
            int row16 = idx >> 4, c4 = idx & 15;
            int grow = m0 + wr * 64 + mf * 16 + row16;
            int gcol = n0 + wc * 64 + c4 * 4;
            if (grow < 1216 && gcol < Vv) {
                int ts = grow >> 6, b = grow & 63;
                f32x4 v = *(f32x4*)&wb[w][row16][c4 * 4];
                if (ts >= dlen[b]) v = (f32x4){0.f, 0.f, 0.f, 0.f};
                __builtin_nontemporal_store(v,
                    (f32x4*)&out[OUT_PRED + ((long long)b * Tt + ts) * Vv + gcol]);
            }
        }
        asm volatile("s_waitcnt vmcnt(0)" ::: "memory");
    }
}

extern "C" void kernel_launch(void* const* d_in, const int* in_sizes, int n_in,
                              void* d_out, int out_size, void* d_ws, size_t ws_size,
                              hipStream_t stream) {
    const float* encoder_out      = (const float*)d_in[0];
    const int*   encoded_captions = (const int*)d_in[1];
    const int*   caption_lengths  = (const int*)d_in[2];
    const float* emb       = (const float*)d_in[3];
    const float* W_ih      = (const float*)d_in[4];
    const float* b_ih      = (const float*)d_in[5];
    const float* W_hh      = (const float*)d_in[6];
    const float* b_hh      = (const float*)d_in[7];
    const float* W_init_h  = (const float*)d_in[8];
    const float* b_init_h  = (const float*)d_in[9];
    const float* W_init_c  = (const float*)d_in[10];
    const float* b_init_c  = (const float*)d_in[11];
    const float* W_fbeta   = (const float*)d_in[12];
    const float* b_fbeta   = (const float*)d_in[13];
    const float* W_fc      = (const float*)d_in[14];
    const float* b_fc      = (const float*)d_in[15];
    const float* W_enc_att = (const float*)d_in[16];
    const float* b_enc_att = (const float*)d_in[17];
    const float* W_dec_att = (const float*)d_in[18];
    const float* b_dec_att = (const float*)d_in[19];
    const float* W_full_att = (const float*)d_in[20];
    const float* b_full_att = (const float*)d_in[21];
    float* out = (float*)d_out;

    char* p = (char*)d_ws;
    auto alloc = [&](size_t bytes) { char* r = p; p += (bytes + 255) & ~255ull; return r; };
    int* sind   = (int*)alloc(64 * 4);
    int* dlen   = (int*)alloc(64 * 4);
    int* caps_s = (int*)alloc(Bb * Lc * 4);
    float* c_st  = (float*)alloc(Bb * Dd * 4);
    float* ag    = (float*)alloc((size_t)Bb * K2 * 4);
    float* b_ag  = (float*)alloc(K2 * 4);
    float* bsum  = (float*)alloc(G4 * 4);
    float* b_hc  = (float*)alloc(1024 * 4);
    ushort_t* mean_bf = (ushort_t*)alloc((size_t)Bb * ENCd * 2);
    ushort_t* hball   = (ushort_t*)alloc((size_t)(Tt + 2) * Bb * Dd * 2);
    ushort_t* x2all   = (ushort_t*)alloc((size_t)Tt * Bb * K2 * 2);        // 6.2 MB
    ushort_t* att1    = (ushort_t*)alloc((size_t)Bb * Pp * Aa * 2);
    ushort_t* W_enc   = (ushort_t*)alloc((size_t)Aa * ENCd * 2);
    ushort_t* W_ag    = (ushort_t*)alloc((size_t)K2 * Dd * 2);
    ushort_t* W_cat   = (ushort_t*)alloc((size_t)G4 * KG * 2);
    ushort_t* W_fcb   = (ushort_t*)alloc((size_t)NPAD * Dd * 2);
    ushort_t* W_hcb   = (ushort_t*)alloc((size_t)1024 * ENCd * 2);
    ushort_t* enc_bf  = (ushort_t*)alloc((size_t)Bb * Pp * ENCd * 2);

    k_sort<<<1, 64, 0, stream>>>(caption_lengths, encoded_captions, out, sind, dlen, caps_s);
    k_cvtall<<<15496, 256, 0, stream>>>(W_dec_att, W_fbeta, W_ih, W_hh, W_fc, W_enc_att,
                                        W_init_h, W_init_c, W_ag, W_cat, W_fcb, W_enc, W_hcb);
    k_bias<<<10, 256, 0, stream>>>(b_dec_att, b_fbeta, b_ih, b_hh, b_init_h, b_init_c,
                                   b_ag, bsum, b_hc);
    k_emball<<<Tt * Bb, 256, 0, stream>>>(emb, caps_s, x2all);
    k_enccvt<<<2048, 256, 0, stream>>>(encoder_out, sind, enc_bf);
    k_meanenc<<<64, 1024, 0, stream>>>(enc_bf, mean_bf);
    k_h0c0<<<16, 256, 0, stream>>>(mean_bf, W_hcb, b_hc, hball, c_st);
    k_att1<<<392, 256, 0, stream>>>(enc_bf, W_enc, b_enc_att, att1);

    for (int t = 0; t < Tt; ++t) {
        const ushort_t* hcur = hball + (size_t)t * Bb * Dd;
        ushort_t* hnext = hball + (size_t)(t + 1) * Bb * Dd;
        ushort_t* x2 = x2all + (size_t)t * Bb * K2;
        k_ag<<<160, 256, 0, stream>>>(hcur, W_ag, b_ag, ag);
        k_esmawe<<<256, 1024, 0, stream>>>(att1, ag, W_full_att, b_full_att, enc_bf,
            x2, out, dlen, t);
        k_gates<<<dim3(32, 4), 512, 0, stream>>>(x2, hcur, W_cat, bsum, hnext, c_st, dlen, t);
    }
    k_preds<<<790, 256, 0, stream>>>(hball + (size_t)Bb * Dd, W_fcb, b_fc, dlen, out);
}